// Round 1
// baseline (3181.085 us; speedup 1.0000x reference)
//
#include <hip/hip_runtime.h>
#include <hip/hip_bf16.h>
#include <math.h>

// GraphSAGE 2-layer, mean aggregation, N=100000, F=500, hid=8, classes=10.
// Key transform: project features BEFORE edge aggregation (linearity of mean).

__global__ __launch_bounds__(256) void proj1_kernel(
    const float* __restrict__ x,
    const float* __restrict__ W1l,   // [8,500]
    const float* __restrict__ W1r,   // [8,500]
    float* __restrict__ y,           // [N,16]: cols 0-7 = x@W1l.T, 8-15 = x@W1r.T
    int N)
{
    __shared__ __align__(16) float wlds[16 * 500];
    for (int idx = threadIdx.x; idx < 16 * 500; idx += blockDim.x) {
        int k = idx / 500, j = idx - k * 500;
        wlds[idx] = (k < 8) ? W1l[k * 500 + j] : W1r[(k - 8) * 500 + j];
    }
    __syncthreads();

    const int lane = threadIdx.x & 63;
    const int wv   = threadIdx.x >> 6;
    const int s    = lane >> 4;      // node slot within wave (0..3)
    const int m    = lane & 15;      // output column (0..15)
    const float4* wrow = reinterpret_cast<const float4*>(wlds + m * 500);

    const int gw = blockIdx.x * 4 + wv;     // global wave id
    const int nw = gridDim.x * 4;
    const int nq = (N + 3) >> 2;            // node quads

    for (int q = gw; q < nq; q += nw) {
        int node = (q << 2) + s;
        if (node >= N) continue;
        const float4* xr = reinterpret_cast<const float4*>(x + (size_t)node * 500);
        float acc = 0.f;
        #pragma unroll 5
        for (int j4 = 0; j4 < 125; ++j4) {
            float4 xv = xr[j4];     // broadcast across 16 lanes (same addr)
            float4 wv4 = wrow[j4];  // LDS, 16 distinct addrs
            acc += xv.x * wv4.x + xv.y * wv4.y + xv.z * wv4.z + xv.w * wv4.w;
        }
        y[(size_t)node * 16 + m] = acc;
    }
}

__global__ __launch_bounds__(256) void agg1_kernel(
    const int* __restrict__ ei,   // [2,E]: src row then dst row
    int E,
    const float* __restrict__ y,  // [N,16]
    float* __restrict__ agg1,     // [N,8] zero-initialized
    float* __restrict__ cnt)      // [N]   zero-initialized
{
    int stride = gridDim.x * blockDim.x;
    for (int e = blockIdx.x * blockDim.x + threadIdx.x; e < E; e += stride) {
        int s = ei[e];
        int d = ei[E + e];
        const float4* yr = reinterpret_cast<const float4*>(y + (size_t)s * 16);
        float4 a = yr[0];
        float4 b = yr[1];
        float* o = agg1 + (size_t)d * 8;
        atomicAdd(o + 0, a.x); atomicAdd(o + 1, a.y);
        atomicAdd(o + 2, a.z); atomicAdd(o + 3, a.w);
        atomicAdd(o + 4, b.x); atomicAdd(o + 5, b.y);
        atomicAdd(o + 6, b.z); atomicAdd(o + 7, b.w);
        atomicAdd(cnt + d, 1.0f);
    }
}

__global__ __launch_bounds__(256) void fin1_proj2_kernel(
    const float* __restrict__ agg1,  // [N,8]
    const float* __restrict__ cnt,   // [N]
    const float* __restrict__ y,     // [N,16] (cols 8..15 = r-branch)
    const float* __restrict__ b1,    // [8]
    const float* __restrict__ W2l,   // [10,8]
    const float* __restrict__ b2,    // [10]
    const float* __restrict__ W2r,   // [10,8]
    float* __restrict__ zl,          // [N,12] (10 used)
    float* __restrict__ zrb,         // [N,12] (10 used) = b2 + h@W2r.T
    int N)
{
    int stride = gridDim.x * blockDim.x;
    for (int i = blockIdx.x * blockDim.x + threadIdx.x; i < N; i += stride) {
        float inv = 1.f / fmaxf(cnt[i], 1.f);
        const float* ar = agg1 + (size_t)i * 8;
        const float* rr = y + (size_t)i * 16 + 8;
        float h[8];
        #pragma unroll
        for (int t = 0; t < 8; ++t) {
            float v = ar[t] * inv + b1[t] + rr[t];
            h[t] = v > 0.f ? v : expm1f(v);   // ELU(alpha=1)
        }
        float* zlr = zl  + (size_t)i * 12;
        float* zrr = zrb + (size_t)i * 12;
        #pragma unroll
        for (int k = 0; k < 10; ++k) {
            float al = 0.f;
            float arv = b2[k];
            #pragma unroll
            for (int t = 0; t < 8; ++t) {
                al  += W2l[k * 8 + t] * h[t];
                arv += W2r[k * 8 + t] * h[t];
            }
            zlr[k] = al;
            zrr[k] = arv;
        }
    }
}

__global__ __launch_bounds__(256) void agg2_kernel(
    const int* __restrict__ ei,
    int E,
    const float* __restrict__ zl,   // [N,12]
    float* __restrict__ agg2)       // [N,12] zero-initialized
{
    int stride = gridDim.x * blockDim.x;
    for (int e = blockIdx.x * blockDim.x + threadIdx.x; e < E; e += stride) {
        int s = ei[e];
        int d = ei[E + e];
        const float* zr = zl + (size_t)s * 12;
        const float4* z4 = reinterpret_cast<const float4*>(zr);
        float4 a = z4[0];
        float4 b = z4[1];
        float2 c = reinterpret_cast<const float2*>(zr)[4];
        float* o = agg2 + (size_t)d * 12;
        atomicAdd(o + 0, a.x); atomicAdd(o + 1, a.y);
        atomicAdd(o + 2, a.z); atomicAdd(o + 3, a.w);
        atomicAdd(o + 4, b.x); atomicAdd(o + 5, b.y);
        atomicAdd(o + 6, b.z); atomicAdd(o + 7, b.w);
        atomicAdd(o + 8, c.x); atomicAdd(o + 9, c.y);
    }
}

__global__ __launch_bounds__(256) void final_kernel(
    const float* __restrict__ agg2,  // [N,12]
    const float* __restrict__ cnt,
    const float* __restrict__ zrb,   // [N,12]
    float* __restrict__ out,         // [N,10]
    int N)
{
    int stride = gridDim.x * blockDim.x;
    for (int i = blockIdx.x * blockDim.x + threadIdx.x; i < N; i += stride) {
        float inv = 1.f / fmaxf(cnt[i], 1.f);
        const float* ag = agg2 + (size_t)i * 12;
        const float* zr = zrb  + (size_t)i * 12;
        float v[10];
        float mx = -1e30f;
        #pragma unroll
        for (int k = 0; k < 10; ++k) {
            v[k] = ag[k] * inv + zr[k];
            mx = fmaxf(mx, v[k]);
        }
        float ssum = 0.f;
        #pragma unroll
        for (int k = 0; k < 10; ++k) ssum += expf(v[k] - mx);
        float lse = mx + logf(ssum);
        float* o = out + (size_t)i * 10;
        #pragma unroll
        for (int k = 0; k < 10; ++k) o[k] = v[k] - lse;
    }
}

extern "C" void kernel_launch(void* const* d_in, const int* in_sizes, int n_in,
                              void* d_out, int out_size, void* d_ws, size_t ws_size,
                              hipStream_t stream) {
    const float* x   = (const float*)d_in[0];
    const int*   ei  = (const int*)d_in[1];
    const float* W1l = (const float*)d_in[2];
    const float* b1l = (const float*)d_in[3];
    const float* W1r = (const float*)d_in[4];
    const float* W2l = (const float*)d_in[5];
    const float* b2l = (const float*)d_in[6];
    const float* W2r = (const float*)d_in[7];
    float* out = (float*)d_out;

    const int N = in_sizes[0] / 500;
    const int E = in_sizes[1] / 2;

    float* ws   = (float*)d_ws;
    float* cnt  = ws;                      // [N]
    float* agg1 = ws + (size_t)N;          // [N,8]
    float* agg2 = ws + (size_t)9  * N;     // [N,12]
    float* y    = ws + (size_t)21 * N;     // [N,16]
    float* zl   = ws + (size_t)37 * N;     // [N,12]
    float* zrb  = ws + (size_t)49 * N;     // [N,12]

    // zero the atomic accumulation regions (cnt, agg1, agg2 are contiguous)
    hipMemsetAsync(ws, 0, (size_t)21 * N * sizeof(float), stream);

    proj1_kernel<<<2048, 256, 0, stream>>>(x, W1l, W1r, y, N);
    agg1_kernel<<<4096, 256, 0, stream>>>(ei, E, y, agg1, cnt);
    fin1_proj2_kernel<<<(N + 255) / 256, 256, 0, stream>>>(
        agg1, cnt, y, b1l, W2l, b2l, W2r, zl, zrb, N);
    agg2_kernel<<<4096, 256, 0, stream>>>(ei, E, zl, agg2);
    final_kernel<<<(N + 255) / 256, 256, 0, stream>>>(agg2, cnt, zrb, out, N);
}

// Round 2
// 823.576 us; speedup vs baseline: 3.8625x; 3.8625x over previous
//
#include <hip/hip_runtime.h>
#include <hip/hip_bf16.h>
#include <math.h>

// GraphSAGE 2-layer, mean aggregation, N=100000, F=500, hid=8, classes=10.
// Project-before-aggregate + per-launch CSR build (pull aggregation, no f32 atomics).

__global__ __launch_bounds__(256) void proj1_kernel(
    const float* __restrict__ x,
    const float* __restrict__ W1l,   // [8,500]
    const float* __restrict__ W1r,   // [8,500]
    float* __restrict__ y,           // [N,16]: cols 0-7 = x@W1l.T, 8-15 = x@W1r.T
    int N)
{
    __shared__ __align__(16) float wlds[16 * 500];
    for (int idx = threadIdx.x; idx < 16 * 500; idx += blockDim.x) {
        int k = idx / 500, j = idx - k * 500;
        wlds[idx] = (k < 8) ? W1l[k * 500 + j] : W1r[(k - 8) * 500 + j];
    }
    __syncthreads();

    const int lane = threadIdx.x & 63;
    const int wv   = threadIdx.x >> 6;
    const int s    = lane >> 4;      // node slot within wave (0..3)
    const int m    = lane & 15;      // output column (0..15)
    const float4* wrow = reinterpret_cast<const float4*>(wlds + m * 500);

    const int gw = blockIdx.x * 4 + wv;     // global wave id
    const int nw = gridDim.x * 4;
    const int nq = (N + 3) >> 2;            // node quads

    for (int q = gw; q < nq; q += nw) {
        int node = (q << 2) + s;
        if (node >= N) continue;
        const float4* xr = reinterpret_cast<const float4*>(x + (size_t)node * 500);
        float acc = 0.f;
        #pragma unroll 5
        for (int j4 = 0; j4 < 125; ++j4) {
            float4 xv = xr[j4];     // broadcast across 16 lanes (same addr)
            float4 wv4 = wrow[j4];  // LDS, 16 distinct addrs
            acc += xv.x * wv4.x + xv.y * wv4.y + xv.z * wv4.z + xv.w * wv4.w;
        }
        y[(size_t)node * 16 + m] = acc;
    }
}

__global__ __launch_bounds__(256) void deg_kernel(
    const int* __restrict__ ei, int E, int* __restrict__ deg)
{
    int stride = gridDim.x * blockDim.x;
    for (int e = blockIdx.x * blockDim.x + threadIdx.x; e < E; e += stride)
        atomicAdd(deg + ei[E + e], 1);
}

// Single-block exclusive scan of deg[0..N) -> off[0..N)
__global__ __launch_bounds__(1024) void scan_kernel(
    const int* __restrict__ deg, int* __restrict__ off, int N)
{
    __shared__ int lds[1024];
    const int t = threadIdx.x;
    const int chunk = (N + 1023) >> 10;
    const int base = t * chunk;
    const int end = min(base + chunk, N);
    int s = 0;
    for (int i = base; i < end; ++i) s += deg[i];
    lds[t] = s;
    __syncthreads();
    for (int o = 1; o < 1024; o <<= 1) {
        int v = (t >= o) ? lds[t - o] : 0;
        __syncthreads();
        lds[t] += v;
        __syncthreads();
    }
    int run = lds[t] - s;   // exclusive prefix
    for (int i = base; i < end; ++i) { off[i] = run; run += deg[i]; }
}

// off[d] (exclusive start) is atomically bumped; after this kernel off[d] == segment end.
__global__ __launch_bounds__(256) void scatter_kernel(
    const int* __restrict__ ei, int E, int* __restrict__ off, int* __restrict__ csr)
{
    int stride = gridDim.x * blockDim.x;
    for (int e = blockIdx.x * blockDim.x + threadIdx.x; e < E; e += stride) {
        int s = ei[e];
        int d = ei[E + e];
        int p = atomicAdd(off + d, 1);
        csr[p] = s;
    }
}

// Pull-aggregate layer 1 + mean + bias + self term + ELU + both layer-2 projections.
__global__ __launch_bounds__(256) void agg1f_kernel(
    const int* __restrict__ off,    // segment ENDS after scatter
    const int* __restrict__ deg,
    const int* __restrict__ csr,
    const float* __restrict__ y,    // [N,16]
    const float* __restrict__ b1,   // [8]
    const float* __restrict__ W2l,  // [10,8]
    const float* __restrict__ b2,   // [10]
    const float* __restrict__ W2r,  // [10,8]
    float* __restrict__ zl,         // [N,12]
    float* __restrict__ zrb,        // [N,12]
    int N)
{
    int i = blockIdx.x * blockDim.x + threadIdx.x;
    if (i >= N) return;
    const int end = off[i];
    const int d   = deg[i];
    const float4* y4 = reinterpret_cast<const float4*>(y);

    float4 A0 = {0,0,0,0}, B0 = {0,0,0,0}, A1 = {0,0,0,0}, B1 = {0,0,0,0};
    int j = end - d;
    for (; j + 1 < end; j += 2) {
        int s0 = csr[j], s1 = csr[j + 1];
        float4 a0 = y4[(size_t)s0 * 4],     b0 = y4[(size_t)s0 * 4 + 1];
        float4 a1 = y4[(size_t)s1 * 4],     c1 = y4[(size_t)s1 * 4 + 1];
        A0.x += a0.x; A0.y += a0.y; A0.z += a0.z; A0.w += a0.w;
        B0.x += b0.x; B0.y += b0.y; B0.z += b0.z; B0.w += b0.w;
        A1.x += a1.x; A1.y += a1.y; A1.z += a1.z; A1.w += a1.w;
        B1.x += c1.x; B1.y += c1.y; B1.z += c1.z; B1.w += c1.w;
    }
    if (j < end) {
        int s0 = csr[j];
        float4 a0 = y4[(size_t)s0 * 4], b0 = y4[(size_t)s0 * 4 + 1];
        A0.x += a0.x; A0.y += a0.y; A0.z += a0.z; A0.w += a0.w;
        B0.x += b0.x; B0.y += b0.y; B0.z += b0.z; B0.w += b0.w;
    }
    float acc[8] = {A0.x + A1.x, A0.y + A1.y, A0.z + A1.z, A0.w + A1.w,
                    B0.x + B1.x, B0.y + B1.y, B0.z + B1.z, B0.w + B1.w};

    const float inv = 1.f / fmaxf((float)d, 1.f);
    float4 r0 = y4[(size_t)i * 4 + 2];
    float4 r1 = y4[(size_t)i * 4 + 3];
    const float rr[8] = {r0.x, r0.y, r0.z, r0.w, r1.x, r1.y, r1.z, r1.w};

    float h[8];
    #pragma unroll
    for (int t = 0; t < 8; ++t) {
        float v = acc[t] * inv + b1[t] + rr[t];
        h[t] = v > 0.f ? v : expm1f(v);   // ELU(alpha=1)
    }

    float zlv[12], zrv[12];
    #pragma unroll
    for (int k = 0; k < 10; ++k) {
        float al = 0.f, ar = b2[k];
        #pragma unroll
        for (int t = 0; t < 8; ++t) {
            al += W2l[k * 8 + t] * h[t];
            ar += W2r[k * 8 + t] * h[t];
        }
        zlv[k] = al; zrv[k] = ar;
    }
    zlv[10] = zlv[11] = zrv[10] = zrv[11] = 0.f;

    float4* zl4 = reinterpret_cast<float4*>(zl  + (size_t)i * 12);
    float4* zr4 = reinterpret_cast<float4*>(zrb + (size_t)i * 12);
    zl4[0] = make_float4(zlv[0], zlv[1], zlv[2], zlv[3]);
    zl4[1] = make_float4(zlv[4], zlv[5], zlv[6], zlv[7]);
    zl4[2] = make_float4(zlv[8], zlv[9], zlv[10], zlv[11]);
    zr4[0] = make_float4(zrv[0], zrv[1], zrv[2], zrv[3]);
    zr4[1] = make_float4(zrv[4], zrv[5], zrv[6], zrv[7]);
    zr4[2] = make_float4(zrv[8], zrv[9], zrv[10], zrv[11]);
}

// Pull-aggregate layer 2 + mean + r-branch + log-softmax.
__global__ __launch_bounds__(256) void agg2f_kernel(
    const int* __restrict__ off,
    const int* __restrict__ deg,
    const int* __restrict__ csr,
    const float* __restrict__ zl,   // [N,12]
    const float* __restrict__ zrb,  // [N,12]
    float* __restrict__ out,        // [N,10]
    int N)
{
    int i = blockIdx.x * blockDim.x + threadIdx.x;
    if (i >= N) return;
    const int end = off[i];
    const int d   = deg[i];
    const float4* z4 = reinterpret_cast<const float4*>(zl);

    float4 A0 = {0,0,0,0}, B0 = {0,0,0,0}, C0 = {0,0,0,0};
    float4 A1 = {0,0,0,0}, B1 = {0,0,0,0}, C1 = {0,0,0,0};
    int j = end - d;
    for (; j + 1 < end; j += 2) {
        int s0 = csr[j], s1 = csr[j + 1];
        float4 a0 = z4[(size_t)s0 * 3], b0 = z4[(size_t)s0 * 3 + 1], c0 = z4[(size_t)s0 * 3 + 2];
        float4 a1 = z4[(size_t)s1 * 3], b1 = z4[(size_t)s1 * 3 + 1], c1 = z4[(size_t)s1 * 3 + 2];
        A0.x += a0.x; A0.y += a0.y; A0.z += a0.z; A0.w += a0.w;
        B0.x += b0.x; B0.y += b0.y; B0.z += b0.z; B0.w += b0.w;
        C0.x += c0.x; C0.y += c0.y;
        A1.x += a1.x; A1.y += a1.y; A1.z += a1.z; A1.w += a1.w;
        B1.x += b1.x; B1.y += b1.y; B1.z += b1.z; B1.w += b1.w;
        C1.x += c1.x; C1.y += c1.y;
    }
    if (j < end) {
        int s0 = csr[j];
        float4 a0 = z4[(size_t)s0 * 3], b0 = z4[(size_t)s0 * 3 + 1], c0 = z4[(size_t)s0 * 3 + 2];
        A0.x += a0.x; A0.y += a0.y; A0.z += a0.z; A0.w += a0.w;
        B0.x += b0.x; B0.y += b0.y; B0.z += b0.z; B0.w += b0.w;
        C0.x += c0.x; C0.y += c0.y;
    }
    float acc[10] = {A0.x + A1.x, A0.y + A1.y, A0.z + A1.z, A0.w + A1.w,
                     B0.x + B1.x, B0.y + B1.y, B0.z + B1.z, B0.w + B1.w,
                     C0.x + C1.x, C0.y + C1.y};

    const float inv = 1.f / fmaxf((float)d, 1.f);
    const float* zr = zrb + (size_t)i * 12;
    float v[10];
    float mx = -1e30f;
    #pragma unroll
    for (int k = 0; k < 10; ++k) {
        v[k] = acc[k] * inv + zr[k];
        mx = fmaxf(mx, v[k]);
    }
    float ssum = 0.f;
    #pragma unroll
    for (int k = 0; k < 10; ++k) ssum += expf(v[k] - mx);
    float lse = mx + logf(ssum);
    float* o = out + (size_t)i * 10;
    #pragma unroll
    for (int k = 0; k < 10; ++k) o[k] = v[k] - lse;
}

extern "C" void kernel_launch(void* const* d_in, const int* in_sizes, int n_in,
                              void* d_out, int out_size, void* d_ws, size_t ws_size,
                              hipStream_t stream) {
    const float* x   = (const float*)d_in[0];
    const int*   ei  = (const int*)d_in[1];
    const float* W1l = (const float*)d_in[2];
    const float* b1l = (const float*)d_in[3];
    const float* W1r = (const float*)d_in[4];
    const float* W2l = (const float*)d_in[5];
    const float* b2l = (const float*)d_in[6];
    const float* W2r = (const float*)d_in[7];
    float* out = (float*)d_out;

    const int N = in_sizes[0] / 500;
    const int E = in_sizes[1] / 2;

    // workspace layout (ints first, then 16B-aligned floats)
    int* deg = (int*)d_ws;                          // [N]
    int* off = deg + N;                             // [N]
    int* csr = off + N;                             // [E]
    size_t foff = ((size_t)(2 * N + E) * 4 + 15) & ~(size_t)15;
    float* y   = (float*)((char*)d_ws + foff);      // [N,16]
    float* zl  = y  + (size_t)16 * N;               // [N,12]
    float* zrb = zl + (size_t)12 * N;               // [N,12]

    hipMemsetAsync(deg, 0, (size_t)N * sizeof(int), stream);

    proj1_kernel<<<2048, 256, 0, stream>>>(x, W1l, W1r, y, N);
    deg_kernel<<<4096, 256, 0, stream>>>(ei, E, deg);
    scan_kernel<<<1, 1024, 0, stream>>>(deg, off, N);
    scatter_kernel<<<4096, 256, 0, stream>>>(ei, E, off, csr);
    agg1f_kernel<<<(N + 255) / 256, 256, 0, stream>>>(
        off, deg, csr, y, b1l, W2l, b2l, W2r, zl, zrb, N);
    agg2f_kernel<<<(N + 255) / 256, 256, 0, stream>>>(
        off, deg, csr, zl, zrb, out, N);
}

// Round 3
// 569.426 us; speedup vs baseline: 5.5865x; 1.4463x over previous
//
#include <hip/hip_runtime.h>
#include <hip/hip_bf16.h>
#include <math.h>

// GraphSAGE 2-layer, mean aggregation, N=100000, F=500, hid=8, classes=10.
// Project-before-aggregate + bucketed counting-sort CSR (no global atomics)
// + block-per-bucket LDS-accumulated pull aggregation, fully fused epilogues.

#define NBKT_MAX 400      // max buckets (N <= 102400)
#define P_BLOCKS 256      // partition blocks for hist/scatter

__global__ __launch_bounds__(256) void proj1_kernel(
    const float* __restrict__ x,
    const float* __restrict__ W1l,   // [8,500]
    const float* __restrict__ W1r,   // [8,500]
    float* __restrict__ y,           // [N,16]: cols 0-7 = x@W1l.T, 8-15 = x@W1r.T
    int N)
{
    __shared__ __align__(16) float wlds[16 * 500];
    for (int idx = threadIdx.x; idx < 16 * 500; idx += blockDim.x) {
        int k = idx / 500, j = idx - k * 500;
        wlds[idx] = (k < 8) ? W1l[k * 500 + j] : W1r[(k - 8) * 500 + j];
    }
    __syncthreads();

    const int lane = threadIdx.x & 63;
    const int wv   = threadIdx.x >> 6;
    const int s    = lane >> 4;      // node slot within wave (0..3)
    const int m    = lane & 15;      // output column (0..15)
    const float4* wrow = reinterpret_cast<const float4*>(wlds + m * 500);

    const int gw = blockIdx.x * 4 + wv;
    const int nw = gridDim.x * 4;
    const int nq = (N + 3) >> 2;

    for (int q = gw; q < nq; q += nw) {
        int node = (q << 2) + s;
        if (node >= N) continue;
        const float4* xr = reinterpret_cast<const float4*>(x + (size_t)node * 500);
        float acc = 0.f;
        #pragma unroll 5
        for (int j4 = 0; j4 < 125; ++j4) {
            float4 xv = xr[j4];
            float4 wv4 = wrow[j4];
            acc += xv.x * wv4.x + xv.y * wv4.y + xv.z * wv4.z + xv.w * wv4.w;
        }
        y[(size_t)node * 16 + m] = acc;
    }
}

// Per-block LDS histogram over dst buckets (bucket = dst>>8).
__global__ __launch_bounds__(256) void hist_kernel(
    const int* __restrict__ ei, int E, int chunk, int B,
    int* __restrict__ hist_g)            // [B][P_BLOCKS]
{
    __shared__ int h[NBKT_MAX];
    for (int i = threadIdx.x; i < B; i += 256) h[i] = 0;
    __syncthreads();
    const int p = blockIdx.x;
    const int e0 = p * chunk, e1 = min(e0 + chunk, E);
    for (int e = e0 + threadIdx.x; e < e1; e += 256)
        atomicAdd(&h[ei[E + e] >> 8], 1);
    __syncthreads();
    for (int b = threadIdx.x; b < B; b += 256)
        hist_g[b * P_BLOCKS + p] = h[b];
}

// tot[b] = sum_p hist[b][p]
__global__ __launch_bounds__(256) void bsum_kernel(
    const int* __restrict__ hist_g, int* __restrict__ tot)
{
    __shared__ int s[256];
    const int b = blockIdx.x;
    s[threadIdx.x] = hist_g[b * P_BLOCKS + threadIdx.x];
    __syncthreads();
    for (int o = 128; o > 0; o >>= 1) {
        if (threadIdx.x < o) s[threadIdx.x] += s[threadIdx.x + o];
        __syncthreads();
    }
    if (threadIdx.x == 0) tot[b] = s[0];
}

// base[b][p] = bstart[b] + exclusive_scan_p(hist[b][p]); bstart[b] = sum tot[0..b)
__global__ __launch_bounds__(256) void base_kernel(
    const int* __restrict__ hist_g, const int* __restrict__ tot, int B,
    int* __restrict__ base, int* __restrict__ bstart)
{
    __shared__ int sr[256];
    __shared__ int s2[256];
    __shared__ int bs_sh;
    const int b = blockIdx.x, tid = threadIdx.x;

    int part = 0;
    for (int i = tid; i < b; i += 256) part += tot[i];
    sr[tid] = part;
    __syncthreads();
    for (int o = 128; o > 0; o >>= 1) {
        if (tid < o) sr[tid] += sr[tid + o];
        __syncthreads();
    }
    if (tid == 0) bs_sh = sr[0];
    __syncthreads();
    const int bs = bs_sh;

    const int v = hist_g[b * P_BLOCKS + tid];
    s2[tid] = v;
    __syncthreads();
    for (int o = 1; o < 256; o <<= 1) {
        int t = (tid >= o) ? s2[tid - o] : 0;
        __syncthreads();
        s2[tid] += t;
        __syncthreads();
    }
    base[b * P_BLOCKS + tid] = bs + s2[tid] - v;   // exclusive
    if (tid == 0) bstart[b] = bs;
    if (b == B - 1 && tid == 255) bstart[B] = bs + s2[255];
}

// Scatter packed (src | dstLow<<17) into bucket-partitioned csr using LDS cursors.
__global__ __launch_bounds__(256) void scatter2_kernel(
    const int* __restrict__ ei, int E, int chunk, int B,
    const int* __restrict__ base, unsigned* __restrict__ csr)
{
    __shared__ int cur[NBKT_MAX];
    const int p = blockIdx.x;
    for (int b = threadIdx.x; b < B; b += 256) cur[b] = base[b * P_BLOCKS + p];
    __syncthreads();
    const int e0 = p * chunk, e1 = min(e0 + chunk, E);
    for (int e = e0 + threadIdx.x; e < e1; e += 256) {
        int s = ei[e];
        int d = ei[E + e];
        int b = d >> 8;
        int pos = atomicAdd(&cur[b], 1);
        csr[pos] = (unsigned)s | ((unsigned)(d & 255) << 17);
    }
}

// Block-per-bucket layer-1 aggregation + mean + bias + self + ELU + layer-2 projections.
__global__ __launch_bounds__(256) void agg1B_kernel(
    const int* __restrict__ bstart,
    const unsigned* __restrict__ csr,
    const float* __restrict__ y,     // [N,16]
    const float* __restrict__ b1,    // [8]
    const float* __restrict__ W2l,   // [10,8]
    const float* __restrict__ b2,    // [10]
    const float* __restrict__ W2r,   // [10,8]
    float* __restrict__ zl,          // [N,12]
    float* __restrict__ zrb,         // [N,12]
    float* __restrict__ invdeg,      // [N]
    int N)
{
    __shared__ float acc[256 * 9];   // stride 9: bank-spread
    __shared__ int   cnt[256];
    __shared__ float wb[178];        // b1[8] | W2l[80] | b2[10] | W2r[80]
    const int tid = threadIdx.x;
    for (int i = tid; i < 256 * 9; i += 256) acc[i] = 0.f;
    cnt[tid] = 0;
    for (int i = tid; i < 178; i += 256)
        wb[i] = (i < 8) ? b1[i] : (i < 88) ? W2l[i - 8] : (i < 98) ? b2[i - 88] : W2r[i - 98];
    __syncthreads();

    const int b = blockIdx.x;
    const int e0 = bstart[b], e1 = bstart[b + 1];
    const float4* y4 = reinterpret_cast<const float4*>(y);
    for (int e = e0 + tid; e < e1; e += 256) {
        unsigned pk = csr[e];
        int s  = pk & 0x1FFFF;
        int dl = pk >> 17;
        float4 a = y4[(size_t)s * 4];
        float4 c = y4[(size_t)s * 4 + 1];
        float* A = acc + dl * 9;
        atomicAdd(A + 0, a.x); atomicAdd(A + 1, a.y);
        atomicAdd(A + 2, a.z); atomicAdd(A + 3, a.w);
        atomicAdd(A + 4, c.x); atomicAdd(A + 5, c.y);
        atomicAdd(A + 6, c.z); atomicAdd(A + 7, c.w);
        atomicAdd(&cnt[dl], 1);
    }
    __syncthreads();

    const int node = b * 256 + tid;
    if (node >= N) return;
    const float inv = 1.f / fmaxf((float)cnt[tid], 1.f);
    float4 r0 = y4[(size_t)node * 4 + 2];
    float4 r1 = y4[(size_t)node * 4 + 3];
    const float rr[8] = {r0.x, r0.y, r0.z, r0.w, r1.x, r1.y, r1.z, r1.w};
    const float* A = acc + tid * 9;

    float h[8];
    #pragma unroll
    for (int t = 0; t < 8; ++t) {
        float v = A[t] * inv + wb[t] + rr[t];
        h[t] = v > 0.f ? v : expm1f(v);   // ELU(alpha=1)
    }

    float zlv[10], zrv[10];
    #pragma unroll
    for (int k = 0; k < 10; ++k) {
        float al = 0.f, ar = wb[88 + k];
        #pragma unroll
        for (int t = 0; t < 8; ++t) {
            al += wb[8 + k * 8 + t]  * h[t];
            ar += wb[98 + k * 8 + t] * h[t];
        }
        zlv[k] = al; zrv[k] = ar;
    }

    float4* zl4 = reinterpret_cast<float4*>(zl  + (size_t)node * 12);
    float4* zr4 = reinterpret_cast<float4*>(zrb + (size_t)node * 12);
    zl4[0] = make_float4(zlv[0], zlv[1], zlv[2], zlv[3]);
    zl4[1] = make_float4(zlv[4], zlv[5], zlv[6], zlv[7]);
    zl4[2] = make_float4(zlv[8], zlv[9], 0.f, 0.f);
    zr4[0] = make_float4(zrv[0], zrv[1], zrv[2], zrv[3]);
    zr4[1] = make_float4(zrv[4], zrv[5], zrv[6], zrv[7]);
    zr4[2] = make_float4(zrv[8], zrv[9], 0.f, 0.f);
    invdeg[node] = inv;
}

// Block-per-bucket layer-2 aggregation + mean + r-branch + log-softmax.
__global__ __launch_bounds__(256) void agg2B_kernel(
    const int* __restrict__ bstart,
    const unsigned* __restrict__ csr,
    const float* __restrict__ zl,    // [N,12]
    const float* __restrict__ zrb,   // [N,12]
    const float* __restrict__ invdeg,
    float* __restrict__ out,         // [N,10]
    int N)
{
    __shared__ float acc[256 * 11];  // stride 11: bank-spread (10 used)
    const int tid = threadIdx.x;
    for (int i = tid; i < 256 * 11; i += 256) acc[i] = 0.f;
    __syncthreads();

    const int b = blockIdx.x;
    const int e0 = bstart[b], e1 = bstart[b + 1];
    for (int e = e0 + tid; e < e1; e += 256) {
        unsigned pk = csr[e];
        int s  = pk & 0x1FFFF;
        int dl = pk >> 17;
        const float* zr = zl + (size_t)s * 12;
        float4 a = *reinterpret_cast<const float4*>(zr);
        float4 c = *reinterpret_cast<const float4*>(zr + 4);
        float2 g = *reinterpret_cast<const float2*>(zr + 8);
        float* A = acc + dl * 11;
        atomicAdd(A + 0, a.x); atomicAdd(A + 1, a.y);
        atomicAdd(A + 2, a.z); atomicAdd(A + 3, a.w);
        atomicAdd(A + 4, c.x); atomicAdd(A + 5, c.y);
        atomicAdd(A + 6, c.z); atomicAdd(A + 7, c.w);
        atomicAdd(A + 8, g.x); atomicAdd(A + 9, g.y);
    }
    __syncthreads();

    const int node = b * 256 + tid;
    if (node >= N) return;
    const float inv = invdeg[node];
    const float* zr = zrb + (size_t)node * 12;
    const float* A = acc + tid * 11;
    float v[10];
    float mx = -1e30f;
    #pragma unroll
    for (int k = 0; k < 10; ++k) {
        v[k] = A[k] * inv + zr[k];
        mx = fmaxf(mx, v[k]);
    }
    float ssum = 0.f;
    #pragma unroll
    for (int k = 0; k < 10; ++k) ssum += expf(v[k] - mx);
    const float lse = mx + logf(ssum);
    float2* o = reinterpret_cast<float2*>(out + (size_t)node * 10);
    o[0] = make_float2(v[0] - lse, v[1] - lse);
    o[1] = make_float2(v[2] - lse, v[3] - lse);
    o[2] = make_float2(v[4] - lse, v[5] - lse);
    o[3] = make_float2(v[6] - lse, v[7] - lse);
    o[4] = make_float2(v[8] - lse, v[9] - lse);
}

extern "C" void kernel_launch(void* const* d_in, const int* in_sizes, int n_in,
                              void* d_out, int out_size, void* d_ws, size_t ws_size,
                              hipStream_t stream) {
    const float* x   = (const float*)d_in[0];
    const int*   ei  = (const int*)d_in[1];
    const float* W1l = (const float*)d_in[2];
    const float* b1l = (const float*)d_in[3];
    const float* W1r = (const float*)d_in[4];
    const float* W2l = (const float*)d_in[5];
    const float* b2l = (const float*)d_in[6];
    const float* W2r = (const float*)d_in[7];
    float* out = (float*)d_out;

    const int N = in_sizes[0] / 500;
    const int E = in_sizes[1] / 2;
    const int B = (N + 255) >> 8;             // buckets of 256 nodes
    const int chunk = (E + P_BLOCKS - 1) / P_BLOCKS;

    // workspace: ints first, then 16B-aligned floats
    int* hist_g  = (int*)d_ws;                       // [B*256]
    int* tot     = hist_g + (size_t)B * 256;         // [B]
    int* bstart  = tot + B;                          // [B+1]
    int* base    = bstart + (B + 1);                 // [B*256]
    unsigned* csr = (unsigned*)(base + (size_t)B * 256); // [E]
    size_t ioff = ((char*)(csr + E) - (char*)d_ws + 15) & ~(size_t)15;
    float* y      = (float*)((char*)d_ws + ioff);    // [N,16]
    float* zl     = y   + (size_t)16 * N;            // [N,12]
    float* zrb    = zl  + (size_t)12 * N;            // [N,12]
    float* invdeg = zrb + (size_t)12 * N;            // [N]

    proj1_kernel<<<2048, 256, 0, stream>>>(x, W1l, W1r, y, N);
    hist_kernel<<<P_BLOCKS, 256, 0, stream>>>(ei, E, chunk, B, hist_g);
    bsum_kernel<<<B, 256, 0, stream>>>(hist_g, tot);
    base_kernel<<<B, 256, 0, stream>>>(hist_g, tot, B, base, bstart);
    scatter2_kernel<<<P_BLOCKS, 256, 0, stream>>>(ei, E, chunk, B, base, csr);
    agg1B_kernel<<<B, 256, 0, stream>>>(bstart, csr, y, b1l, W2l, b2l, W2r,
                                        zl, zrb, invdeg, N);
    agg2B_kernel<<<B, 256, 0, stream>>>(bstart, csr, zl, zrb, invdeg, out, N);
}

// Round 4
// 559.706 us; speedup vs baseline: 5.6835x; 1.0174x over previous
//
#include <hip/hip_runtime.h>
#include <hip/hip_bf16.h>
#include <math.h>

// GraphSAGE 2-layer, mean aggregation, N=100000, F=500, hid=8, classes=10.
// Project-before-aggregate + bucketed counting-sort CSR (no global atomics)
// + block-per-bucket LDS-accumulated pull aggregation, fully fused epilogues.
// Round 4: 128-node buckets + 512-thread blocks for occupancy (was 12.5%).

#define NBKT_MAX 800      // max buckets (N <= 102400)
#define P_BLOCKS 256      // partition blocks for hist/scatter
#define BSH 7             // bucket shift: 128 nodes/bucket
#define BSZ 128

__global__ __launch_bounds__(256) void proj1_kernel(
    const float* __restrict__ x,
    const float* __restrict__ W1l,   // [8,500]
    const float* __restrict__ W1r,   // [8,500]
    float* __restrict__ y,           // [N,16]: cols 0-7 = x@W1l.T, 8-15 = x@W1r.T
    int N)
{
    __shared__ __align__(16) float wlds[16 * 500];
    for (int idx = threadIdx.x; idx < 16 * 500; idx += blockDim.x) {
        int k = idx / 500, j = idx - k * 500;
        wlds[idx] = (k < 8) ? W1l[k * 500 + j] : W1r[(k - 8) * 500 + j];
    }
    __syncthreads();

    const int lane = threadIdx.x & 63;
    const int wv   = threadIdx.x >> 6;
    const int s    = lane >> 4;      // node slot within wave (0..3)
    const int m    = lane & 15;      // output column (0..15)
    const float4* wrow = reinterpret_cast<const float4*>(wlds + m * 500);

    const int gw = blockIdx.x * 4 + wv;
    const int nw = gridDim.x * 4;
    const int nq = (N + 3) >> 2;

    for (int q = gw; q < nq; q += nw) {
        int node = (q << 2) + s;
        if (node >= N) continue;
        const float4* xr = reinterpret_cast<const float4*>(x + (size_t)node * 500);
        float acc = 0.f;
        #pragma unroll 5
        for (int j4 = 0; j4 < 125; ++j4) {
            float4 xv = xr[j4];
            float4 wv4 = wrow[j4];
            acc += xv.x * wv4.x + xv.y * wv4.y + xv.z * wv4.z + xv.w * wv4.w;
        }
        y[(size_t)node * 16 + m] = acc;
    }
}

// Per-block LDS histogram over dst buckets (bucket = dst>>BSH).
__global__ __launch_bounds__(512) void hist_kernel(
    const int* __restrict__ ei, int E, int chunk, int B,
    int* __restrict__ hist_g)            // [B][P_BLOCKS]
{
    __shared__ int h[NBKT_MAX];
    for (int i = threadIdx.x; i < B; i += 512) h[i] = 0;
    __syncthreads();
    const int p = blockIdx.x;
    const int e0 = p * chunk, e1 = min(e0 + chunk, E);
    for (int e = e0 + threadIdx.x; e < e1; e += 512)
        atomicAdd(&h[ei[E + e] >> BSH], 1);
    __syncthreads();
    for (int b = threadIdx.x; b < B; b += 512)
        hist_g[b * P_BLOCKS + p] = h[b];
}

// tot[b] = sum_p hist[b][p]
__global__ __launch_bounds__(256) void bsum_kernel(
    const int* __restrict__ hist_g, int* __restrict__ tot)
{
    __shared__ int s[256];
    const int b = blockIdx.x;
    s[threadIdx.x] = hist_g[b * P_BLOCKS + threadIdx.x];
    __syncthreads();
    for (int o = 128; o > 0; o >>= 1) {
        if (threadIdx.x < o) s[threadIdx.x] += s[threadIdx.x + o];
        __syncthreads();
    }
    if (threadIdx.x == 0) tot[b] = s[0];
}

// base[b][p] = bstart[b] + exclusive_scan_p(hist[b][p]); bstart[b] = sum tot[0..b)
__global__ __launch_bounds__(256) void base_kernel(
    const int* __restrict__ hist_g, const int* __restrict__ tot, int B,
    int* __restrict__ base, int* __restrict__ bstart)
{
    __shared__ int sr[256];
    __shared__ int s2[256];
    __shared__ int bs_sh;
    const int b = blockIdx.x, tid = threadIdx.x;

    int part = 0;
    for (int i = tid; i < b; i += 256) part += tot[i];
    sr[tid] = part;
    __syncthreads();
    for (int o = 128; o > 0; o >>= 1) {
        if (tid < o) sr[tid] += sr[tid + o];
        __syncthreads();
    }
    if (tid == 0) bs_sh = sr[0];
    __syncthreads();
    const int bs = bs_sh;

    const int v = hist_g[b * P_BLOCKS + tid];
    s2[tid] = v;
    __syncthreads();
    for (int o = 1; o < 256; o <<= 1) {
        int t = (tid >= o) ? s2[tid - o] : 0;
        __syncthreads();
        s2[tid] += t;
        __syncthreads();
    }
    base[b * P_BLOCKS + tid] = bs + s2[tid] - v;   // exclusive
    if (tid == 0) bstart[b] = bs;
    if (b == B - 1 && tid == 255) bstart[B] = bs + s2[255];
}

// Scatter packed (src | dstLow<<17) into bucket-partitioned csr using LDS cursors.
__global__ __launch_bounds__(512) void scatter2_kernel(
    const int* __restrict__ ei, int E, int chunk, int B,
    const int* __restrict__ base, unsigned* __restrict__ csr)
{
    __shared__ int cur[NBKT_MAX];
    const int p = blockIdx.x;
    for (int b = threadIdx.x; b < B; b += 512) cur[b] = base[b * P_BLOCKS + p];
    __syncthreads();
    const int e0 = p * chunk, e1 = min(e0 + chunk, E);
    for (int e = e0 + threadIdx.x; e < e1; e += 512) {
        int s = ei[e];
        int d = ei[E + e];
        int b = d >> BSH;
        int pos = atomicAdd(&cur[b], 1);
        csr[pos] = (unsigned)s | ((unsigned)(d & (BSZ - 1)) << 17);
    }
}

// Block-per-bucket layer-1 aggregation + mean + bias + self + ELU + layer-2 projections.
__global__ __launch_bounds__(512) void agg1B_kernel(
    const int* __restrict__ bstart,
    const unsigned* __restrict__ csr,
    const float* __restrict__ y,     // [N,16]
    const float* __restrict__ b1,    // [8]
    const float* __restrict__ W2l,   // [10,8]
    const float* __restrict__ b2,    // [10]
    const float* __restrict__ W2r,   // [10,8]
    float* __restrict__ zl,          // [N,12]
    float* __restrict__ zrb,         // [N,12]
    float* __restrict__ invdeg,      // [N]
    int N)
{
    __shared__ float acc[BSZ * 9];   // stride 9: bank-spread
    __shared__ int   cnt[BSZ];
    __shared__ float wb[178];        // b1[8] | W2l[80] | b2[10] | W2r[80]
    const int tid = threadIdx.x;
    for (int i = tid; i < BSZ * 9; i += 512) acc[i] = 0.f;
    if (tid < BSZ) cnt[tid] = 0;
    if (tid < 178)
        wb[tid] = (tid < 8) ? b1[tid] : (tid < 88) ? W2l[tid - 8]
                 : (tid < 98) ? b2[tid - 88] : W2r[tid - 98];
    __syncthreads();

    const int b = blockIdx.x;
    const int e0 = bstart[b], e1 = bstart[b + 1];
    const float4* y4 = reinterpret_cast<const float4*>(y);
    for (int e = e0 + tid; e < e1; e += 512) {
        unsigned pk = csr[e];
        int s  = pk & 0x1FFFF;
        int dl = pk >> 17;
        float4 a = y4[(size_t)s * 4];
        float4 c = y4[(size_t)s * 4 + 1];
        float* A = acc + dl * 9;
        atomicAdd(A + 0, a.x); atomicAdd(A + 1, a.y);
        atomicAdd(A + 2, a.z); atomicAdd(A + 3, a.w);
        atomicAdd(A + 4, c.x); atomicAdd(A + 5, c.y);
        atomicAdd(A + 6, c.z); atomicAdd(A + 7, c.w);
        atomicAdd(&cnt[dl], 1);
    }
    __syncthreads();

    if (tid >= BSZ) return;
    const int node = b * BSZ + tid;
    if (node >= N) return;
    const float inv = 1.f / fmaxf((float)cnt[tid], 1.f);
    float4 r0 = y4[(size_t)node * 4 + 2];
    float4 r1 = y4[(size_t)node * 4 + 3];
    const float rr[8] = {r0.x, r0.y, r0.z, r0.w, r1.x, r1.y, r1.z, r1.w};
    const float* A = acc + tid * 9;

    float h[8];
    #pragma unroll
    for (int t = 0; t < 8; ++t) {
        float v = A[t] * inv + wb[t] + rr[t];
        h[t] = v > 0.f ? v : expm1f(v);   // ELU(alpha=1)
    }

    float zlv[10], zrv[10];
    #pragma unroll
    for (int k = 0; k < 10; ++k) {
        float al = 0.f, ar = wb[88 + k];
        #pragma unroll
        for (int t = 0; t < 8; ++t) {
            al += wb[8 + k * 8 + t]  * h[t];
            ar += wb[98 + k * 8 + t] * h[t];
        }
        zlv[k] = al; zrv[k] = ar;
    }

    float4* zl4 = reinterpret_cast<float4*>(zl  + (size_t)node * 12);
    float4* zr4 = reinterpret_cast<float4*>(zrb + (size_t)node * 12);
    zl4[0] = make_float4(zlv[0], zlv[1], zlv[2], zlv[3]);
    zl4[1] = make_float4(zlv[4], zlv[5], zlv[6], zlv[7]);
    zl4[2] = make_float4(zlv[8], zlv[9], 0.f, 0.f);
    zr4[0] = make_float4(zrv[0], zrv[1], zrv[2], zrv[3]);
    zr4[1] = make_float4(zrv[4], zrv[5], zrv[6], zrv[7]);
    zr4[2] = make_float4(zrv[8], zrv[9], 0.f, 0.f);
    invdeg[node] = inv;
}

// Block-per-bucket layer-2 aggregation + mean + r-branch + log-softmax.
__global__ __launch_bounds__(512) void agg2B_kernel(
    const int* __restrict__ bstart,
    const unsigned* __restrict__ csr,
    const float* __restrict__ zl,    // [N,12]
    const float* __restrict__ zrb,   // [N,12]
    const float* __restrict__ invdeg,
    float* __restrict__ out,         // [N,10]
    int N)
{
    __shared__ float acc[BSZ * 11];  // stride 11: bank-spread (10 used)
    const int tid = threadIdx.x;
    for (int i = tid; i < BSZ * 11; i += 512) acc[i] = 0.f;
    __syncthreads();

    const int b = blockIdx.x;
    const int e0 = bstart[b], e1 = bstart[b + 1];
    for (int e = e0 + tid; e < e1; e += 512) {
        unsigned pk = csr[e];
        int s  = pk & 0x1FFFF;
        int dl = pk >> 17;
        const float* zr = zl + (size_t)s * 12;
        float4 a = *reinterpret_cast<const float4*>(zr);
        float4 c = *reinterpret_cast<const float4*>(zr + 4);
        float2 g = *reinterpret_cast<const float2*>(zr + 8);
        float* A = acc + dl * 11;
        atomicAdd(A + 0, a.x); atomicAdd(A + 1, a.y);
        atomicAdd(A + 2, a.z); atomicAdd(A + 3, a.w);
        atomicAdd(A + 4, c.x); atomicAdd(A + 5, c.y);
        atomicAdd(A + 6, c.z); atomicAdd(A + 7, c.w);
        atomicAdd(A + 8, g.x); atomicAdd(A + 9, g.y);
    }
    __syncthreads();

    if (tid >= BSZ) return;
    const int node = b * BSZ + tid;
    if (node >= N) return;
    const float inv = invdeg[node];
    const float* zr = zrb + (size_t)node * 12;
    const float* A = acc + tid * 11;
    float v[10];
    float mx = -1e30f;
    #pragma unroll
    for (int k = 0; k < 10; ++k) {
        v[k] = A[k] * inv + zr[k];
        mx = fmaxf(mx, v[k]);
    }
    float ssum = 0.f;
    #pragma unroll
    for (int k = 0; k < 10; ++k) ssum += expf(v[k] - mx);
    const float lse = mx + logf(ssum);
    float2* o = reinterpret_cast<float2*>(out + (size_t)node * 10);
    o[0] = make_float2(v[0] - lse, v[1] - lse);
    o[1] = make_float2(v[2] - lse, v[3] - lse);
    o[2] = make_float2(v[4] - lse, v[5] - lse);
    o[3] = make_float2(v[6] - lse, v[7] - lse);
    o[4] = make_float2(v[8] - lse, v[9] - lse);
}

extern "C" void kernel_launch(void* const* d_in, const int* in_sizes, int n_in,
                              void* d_out, int out_size, void* d_ws, size_t ws_size,
                              hipStream_t stream) {
    const float* x   = (const float*)d_in[0];
    const int*   ei  = (const int*)d_in[1];
    const float* W1l = (const float*)d_in[2];
    const float* b1l = (const float*)d_in[3];
    const float* W1r = (const float*)d_in[4];
    const float* W2l = (const float*)d_in[5];
    const float* b2l = (const float*)d_in[6];
    const float* W2r = (const float*)d_in[7];
    float* out = (float*)d_out;

    const int N = in_sizes[0] / 500;
    const int E = in_sizes[1] / 2;
    const int B = (N + BSZ - 1) >> BSH;       // buckets of BSZ nodes
    const int chunk = (E + P_BLOCKS - 1) / P_BLOCKS;

    // workspace: ints first, then 16B-aligned floats
    int* hist_g  = (int*)d_ws;                       // [B*P_BLOCKS]
    int* tot     = hist_g + (size_t)B * P_BLOCKS;    // [B]
    int* bstart  = tot + B;                          // [B+1]
    int* base    = bstart + (B + 1);                 // [B*P_BLOCKS]
    unsigned* csr = (unsigned*)(base + (size_t)B * P_BLOCKS); // [E]
    size_t ioff = ((char*)(csr + E) - (char*)d_ws + 15) & ~(size_t)15;
    float* y      = (float*)((char*)d_ws + ioff);    // [N,16]
    float* zl     = y   + (size_t)16 * N;            // [N,12]
    float* zrb    = zl  + (size_t)12 * N;            // [N,12]
    float* invdeg = zrb + (size_t)12 * N;            // [N]

    proj1_kernel<<<2048, 256, 0, stream>>>(x, W1l, W1r, y, N);
    hist_kernel<<<P_BLOCKS, 512, 0, stream>>>(ei, E, chunk, B, hist_g);
    bsum_kernel<<<B, 256, 0, stream>>>(hist_g, tot);
    base_kernel<<<B, 256, 0, stream>>>(hist_g, tot, B, base, bstart);
    scatter2_kernel<<<P_BLOCKS, 512, 0, stream>>>(ei, E, chunk, B, base, csr);
    agg1B_kernel<<<B, 512, 0, stream>>>(bstart, csr, y, b1l, W2l, b2l, W2r,
                                        zl, zrb, invdeg, N);
    agg2B_kernel<<<B, 512, 0, stream>>>(bstart, csr, zl, zrb, invdeg, out, N);
}

// Round 5
// 533.713 us; speedup vs baseline: 5.9603x; 1.0487x over previous
//
#include <hip/hip_runtime.h>
#include <hip/hip_bf16.h>
#include <math.h>

// GraphSAGE 2-layer, mean aggregation, N=100000, F=500, hid=8, classes=10.
// Project-before-aggregate + bucketed counting-sort CSR (no global atomics)
// + block-per-bucket LDS-accumulated pull aggregation, fully fused epilogues.
// Round 5: chunked gathers (k lanes per edge -> few unique cachelines/instr),
// nontemporal loads (L1 bypass), unroll-2 ILP, 64-node buckets.

#define NBKT_MAX 1600     // max buckets (N <= 102400)
#define P_BLOCKS 256      // partition blocks for hist/scatter
#define BSH 6             // bucket shift: 64 nodes/bucket
#define BSZ 64

typedef float f4v __attribute__((ext_vector_type(4)));

__global__ __launch_bounds__(256) void proj1_kernel(
    const float* __restrict__ x,
    const float* __restrict__ W1l,   // [8,500]
    const float* __restrict__ W1r,   // [8,500]
    float* __restrict__ ya,          // [N,8]  = x@W1l.T (aggregated part)
    float* __restrict__ yr,          // [N,8]  = x@W1r.T (self part)
    int N)
{
    __shared__ __align__(16) float wlds[16 * 500];
    for (int idx = threadIdx.x; idx < 16 * 500; idx += blockDim.x) {
        int k = idx / 500, j = idx - k * 500;
        wlds[idx] = (k < 8) ? W1l[k * 500 + j] : W1r[(k - 8) * 500 + j];
    }
    __syncthreads();

    const int lane = threadIdx.x & 63;
    const int wv   = threadIdx.x >> 6;
    const int s    = lane >> 4;      // node slot within wave (0..3)
    const int m    = lane & 15;      // output column (0..15)
    const float4* wrow = reinterpret_cast<const float4*>(wlds + m * 500);

    const int gw = blockIdx.x * 4 + wv;
    const int nw = gridDim.x * 4;
    const int nq = (N + 3) >> 2;

    for (int q = gw; q < nq; q += nw) {
        int node = (q << 2) + s;
        if (node >= N) continue;
        const float4* xr = reinterpret_cast<const float4*>(x + (size_t)node * 500);
        float acc = 0.f;
        #pragma unroll 5
        for (int j4 = 0; j4 < 125; ++j4) {
            float4 xv = xr[j4];
            float4 wv4 = wrow[j4];
            acc += xv.x * wv4.x + xv.y * wv4.y + xv.z * wv4.z + xv.w * wv4.w;
        }
        if (m < 8) ya[(size_t)node * 8 + m] = acc;
        else       yr[(size_t)node * 8 + m - 8] = acc;
    }
}

// Per-block LDS histogram over dst buckets (bucket = dst>>BSH).
__global__ __launch_bounds__(512) void hist_kernel(
    const int* __restrict__ ei, int E, int chunk, int B,
    int* __restrict__ hist_g)            // [B][P_BLOCKS]
{
    __shared__ int h[NBKT_MAX];
    for (int i = threadIdx.x; i < B; i += 512) h[i] = 0;
    __syncthreads();
    const int p = blockIdx.x;
    const int e0 = p * chunk, e1 = min(e0 + chunk, E);
    int e = e0 + threadIdx.x;
    for (; e + 512 < e1; e += 1024) {
        int d0 = ei[E + e], d1 = ei[E + e + 512];
        atomicAdd(&h[d0 >> BSH], 1);
        atomicAdd(&h[d1 >> BSH], 1);
    }
    for (; e < e1; e += 512) atomicAdd(&h[ei[E + e] >> BSH], 1);
    __syncthreads();
    for (int b = threadIdx.x; b < B; b += 512)
        hist_g[(size_t)b * P_BLOCKS + p] = h[b];
}

// tot[b] = sum_p hist[b][p]
__global__ __launch_bounds__(256) void bsum_kernel(
    const int* __restrict__ hist_g, int* __restrict__ tot)
{
    __shared__ int s[256];
    const int b = blockIdx.x;
    s[threadIdx.x] = hist_g[(size_t)b * P_BLOCKS + threadIdx.x];
    __syncthreads();
    for (int o = 128; o > 0; o >>= 1) {
        if (threadIdx.x < o) s[threadIdx.x] += s[threadIdx.x + o];
        __syncthreads();
    }
    if (threadIdx.x == 0) tot[b] = s[0];
}

// In-place: hist_g[b][p] <- bstart[b] + exclusive_scan_p(hist[b][p]).
__global__ __launch_bounds__(256) void base_kernel(
    int* __restrict__ hist_g, const int* __restrict__ tot, int B,
    int* __restrict__ bstart)
{
    __shared__ int sr[256];
    __shared__ int s2[256];
    __shared__ int bs_sh;
    const int b = blockIdx.x, tid = threadIdx.x;

    int part = 0;
    for (int i = tid; i < b; i += 256) part += tot[i];
    sr[tid] = part;
    __syncthreads();
    for (int o = 128; o > 0; o >>= 1) {
        if (tid < o) sr[tid] += sr[tid + o];
        __syncthreads();
    }
    if (tid == 0) bs_sh = sr[0];
    __syncthreads();
    const int bs = bs_sh;

    const int v = hist_g[(size_t)b * P_BLOCKS + tid];
    s2[tid] = v;
    __syncthreads();
    for (int o = 1; o < 256; o <<= 1) {
        int t = (tid >= o) ? s2[tid - o] : 0;
        __syncthreads();
        s2[tid] += t;
        __syncthreads();
    }
    hist_g[(size_t)b * P_BLOCKS + tid] = bs + s2[tid] - v;   // exclusive base
    if (tid == 0) bstart[b] = bs;
    if (b == B - 1 && tid == 255) bstart[B] = bs + s2[255];
}

// Scatter packed (src | dstLow<<17) into bucket-partitioned csr using LDS cursors.
__global__ __launch_bounds__(512) void scatter2_kernel(
    const int* __restrict__ ei, int E, int chunk, int B,
    const int* __restrict__ base, unsigned* __restrict__ csr)
{
    __shared__ int cur[NBKT_MAX];
    const int p = blockIdx.x;
    for (int b = threadIdx.x; b < B; b += 512) cur[b] = base[(size_t)b * P_BLOCKS + p];
    __syncthreads();
    const int e0 = p * chunk, e1 = min(e0 + chunk, E);
    int e = e0 + threadIdx.x;
    for (; e + 512 < e1; e += 1024) {
        int s0 = ei[e],     s1 = ei[e + 512];
        int d0 = ei[E + e], d1 = ei[E + e + 512];
        int p0 = atomicAdd(&cur[d0 >> BSH], 1);
        int p1 = atomicAdd(&cur[d1 >> BSH], 1);
        csr[p0] = (unsigned)s0 | ((unsigned)(d0 & (BSZ - 1)) << 17);
        csr[p1] = (unsigned)s1 | ((unsigned)(d1 & (BSZ - 1)) << 17);
    }
    for (; e < e1; e += 512) {
        int s0 = ei[e], d0 = ei[E + e];
        int p0 = atomicAdd(&cur[d0 >> BSH], 1);
        csr[p0] = (unsigned)s0 | ((unsigned)(d0 & (BSZ - 1)) << 17);
    }
}

// Layer-1 aggregation: 2 lanes per edge (32B row of ya), LDS accumulate,
// fused mean + bias + self + ELU + both layer-2 projections.
__global__ __launch_bounds__(256) void agg1B_kernel(
    const int* __restrict__ bstart,
    const unsigned* __restrict__ csr,
    const float* __restrict__ ya,    // [N,8]
    const float* __restrict__ yr,    // [N,8]
    const float* __restrict__ b1,    // [8]
    const float* __restrict__ W2l,   // [10,8]
    const float* __restrict__ b2,    // [10]
    const float* __restrict__ W2r,   // [10,8]
    float* __restrict__ zl,          // [N,16] padded, 64B rows
    float* __restrict__ zrb,         // [N,12]  (col10 = invdeg)
    int N)
{
    __shared__ float acc[BSZ * 9];
    __shared__ int   cnt[BSZ];
    __shared__ float wb[178];        // b1[8] | W2l[80] | b2[10] | W2r[80]
    const int tid = threadIdx.x;
    for (int i = tid; i < BSZ * 9; i += 256) acc[i] = 0.f;
    if (tid < BSZ) cnt[tid] = 0;
    if (tid < 178)
        wb[tid] = (tid < 8) ? b1[tid] : (tid < 88) ? W2l[tid - 8]
                 : (tid < 98) ? b2[tid - 88] : W2r[tid - 98];
    __syncthreads();

    const int b = blockIdx.x;
    const int e0 = bstart[b], e1 = bstart[b + 1];
    const f4v* ya4 = reinterpret_cast<const f4v*>(ya);
    const int q = tid & 1;
    int e = e0 + (tid >> 1);
    for (; e + 128 < e1; e += 256) {
        unsigned pk0 = csr[e], pk1 = csr[e + 128];
        f4v v0 = __builtin_nontemporal_load(&ya4[(size_t)(pk0 & 0x1FFFFu) * 2 + q]);
        f4v v1 = __builtin_nontemporal_load(&ya4[(size_t)(pk1 & 0x1FFFFu) * 2 + q]);
        int dl0 = pk0 >> 17, dl1 = pk1 >> 17;
        float* A0 = acc + dl0 * 9 + q * 4;
        float* A1 = acc + dl1 * 9 + q * 4;
        atomicAdd(A0 + 0, v0.x); atomicAdd(A0 + 1, v0.y);
        atomicAdd(A0 + 2, v0.z); atomicAdd(A0 + 3, v0.w);
        atomicAdd(A1 + 0, v1.x); atomicAdd(A1 + 1, v1.y);
        atomicAdd(A1 + 2, v1.z); atomicAdd(A1 + 3, v1.w);
        if (q == 0) { atomicAdd(&cnt[dl0], 1); atomicAdd(&cnt[dl1], 1); }
    }
    for (; e < e1; e += 128) {
        unsigned pk0 = csr[e];
        f4v v0 = __builtin_nontemporal_load(&ya4[(size_t)(pk0 & 0x1FFFFu) * 2 + q]);
        int dl0 = pk0 >> 17;
        float* A0 = acc + dl0 * 9 + q * 4;
        atomicAdd(A0 + 0, v0.x); atomicAdd(A0 + 1, v0.y);
        atomicAdd(A0 + 2, v0.z); atomicAdd(A0 + 3, v0.w);
        if (q == 0) atomicAdd(&cnt[dl0], 1);
    }
    __syncthreads();

    if (tid >= BSZ) return;
    const int node = b * BSZ + tid;
    if (node >= N) return;
    const float inv = 1.f / fmaxf((float)cnt[tid], 1.f);
    const float* rrp = yr + (size_t)node * 8;
    const float* A = acc + tid * 9;

    float h[8];
    #pragma unroll
    for (int t = 0; t < 8; ++t) {
        float v = A[t] * inv + wb[t] + rrp[t];
        h[t] = v > 0.f ? v : expm1f(v);   // ELU(alpha=1)
    }

    float zlv[10], zrv[10];
    #pragma unroll
    for (int k = 0; k < 10; ++k) {
        float al = 0.f, ar = wb[88 + k];
        #pragma unroll
        for (int t = 0; t < 8; ++t) {
            al += wb[8 + k * 8 + t]  * h[t];
            ar += wb[98 + k * 8 + t] * h[t];
        }
        zlv[k] = al; zrv[k] = ar;
    }

    float4* zl4w = reinterpret_cast<float4*>(zl + (size_t)node * 16);
    zl4w[0] = make_float4(zlv[0], zlv[1], zlv[2], zlv[3]);
    zl4w[1] = make_float4(zlv[4], zlv[5], zlv[6], zlv[7]);
    zl4w[2] = make_float4(zlv[8], zlv[9], 0.f, 0.f);
    zl4w[3] = make_float4(0.f, 0.f, 0.f, 0.f);
    float4* zr4w = reinterpret_cast<float4*>(zrb + (size_t)node * 12);
    zr4w[0] = make_float4(zrv[0], zrv[1], zrv[2], zrv[3]);
    zr4w[1] = make_float4(zrv[4], zrv[5], zrv[6], zrv[7]);
    zr4w[2] = make_float4(zrv[8], zrv[9], inv, 0.f);   // col10 = invdeg
}

// Layer-2 aggregation: 4 lanes per edge (64B-aligned zl row, q<3 active),
// fused mean + r-branch + log-softmax.
__global__ __launch_bounds__(256) void agg2B_kernel(
    const int* __restrict__ bstart,
    const unsigned* __restrict__ csr,
    const float* __restrict__ zl,    // [N,16]
    const float* __restrict__ zrb,   // [N,12] (col10 = invdeg)
    float* __restrict__ out,         // [N,10]
    int N)
{
    __shared__ float acc[BSZ * 17];
    const int tid = threadIdx.x;
    for (int i = tid; i < BSZ * 17; i += 256) acc[i] = 0.f;
    __syncthreads();

    const int b = blockIdx.x;
    const int e0 = bstart[b], e1 = bstart[b + 1];
    const f4v* zl4 = reinterpret_cast<const f4v*>(zl);
    const int q = tid & 3;
    if (q < 3) {
        int e = e0 + (tid >> 2);
        for (; e + 64 < e1; e += 128) {
            unsigned pk0 = csr[e], pk1 = csr[e + 64];
            f4v v0 = __builtin_nontemporal_load(&zl4[(size_t)(pk0 & 0x1FFFFu) * 4 + q]);
            f4v v1 = __builtin_nontemporal_load(&zl4[(size_t)(pk1 & 0x1FFFFu) * 4 + q]);
            int dl0 = pk0 >> 17, dl1 = pk1 >> 17;
            float* A0 = acc + dl0 * 17 + q * 4;
            float* A1 = acc + dl1 * 17 + q * 4;
            if (q < 2) {
                atomicAdd(A0 + 0, v0.x); atomicAdd(A0 + 1, v0.y);
                atomicAdd(A0 + 2, v0.z); atomicAdd(A0 + 3, v0.w);
                atomicAdd(A1 + 0, v1.x); atomicAdd(A1 + 1, v1.y);
                atomicAdd(A1 + 2, v1.z); atomicAdd(A1 + 3, v1.w);
            } else {
                atomicAdd(A0 + 0, v0.x); atomicAdd(A0 + 1, v0.y);
                atomicAdd(A1 + 0, v1.x); atomicAdd(A1 + 1, v1.y);
            }
        }
        for (; e < e1; e += 64) {
            unsigned pk0 = csr[e];
            f4v v0 = __builtin_nontemporal_load(&zl4[(size_t)(pk0 & 0x1FFFFu) * 4 + q]);
            int dl0 = pk0 >> 17;
            float* A0 = acc + dl0 * 17 + q * 4;
            if (q < 2) {
                atomicAdd(A0 + 0, v0.x); atomicAdd(A0 + 1, v0.y);
                atomicAdd(A0 + 2, v0.z); atomicAdd(A0 + 3, v0.w);
            } else {
                atomicAdd(A0 + 0, v0.x); atomicAdd(A0 + 1, v0.y);
            }
        }
    }
    __syncthreads();

    if (tid >= BSZ) return;
    const int node = b * BSZ + tid;
    if (node >= N) return;
    const float* zr = zrb + (size_t)node * 12;
    const float inv = zr[10];
    const float* A = acc + tid * 17;
    float v[10];
    float mx = -1e30f;
    #pragma unroll
    for (int k = 0; k < 10; ++k) {
        v[k] = A[k] * inv + zr[k];
        mx = fmaxf(mx, v[k]);
    }
    float ssum = 0.f;
    #pragma unroll
    for (int k = 0; k < 10; ++k) ssum += expf(v[k] - mx);
    const float lse = mx + logf(ssum);
    float2* o = reinterpret_cast<float2*>(out + (size_t)node * 10);
    o[0] = make_float2(v[0] - lse, v[1] - lse);
    o[1] = make_float2(v[2] - lse, v[3] - lse);
    o[2] = make_float2(v[4] - lse, v[5] - lse);
    o[3] = make_float2(v[6] - lse, v[7] - lse);
    o[4] = make_float2(v[8] - lse, v[9] - lse);
}

extern "C" void kernel_launch(void* const* d_in, const int* in_sizes, int n_in,
                              void* d_out, int out_size, void* d_ws, size_t ws_size,
                              hipStream_t stream) {
    const float* x   = (const float*)d_in[0];
    const int*   ei  = (const int*)d_in[1];
    const float* W1l = (const float*)d_in[2];
    const float* b1l = (const float*)d_in[3];
    const float* W1r = (const float*)d_in[4];
    const float* W2l = (const float*)d_in[5];
    const float* b2l = (const float*)d_in[6];
    const float* W2r = (const float*)d_in[7];
    float* out = (float*)d_out;

    const int N = in_sizes[0] / 500;
    const int E = in_sizes[1] / 2;
    const int B = (N + BSZ - 1) >> BSH;       // buckets of BSZ nodes
    const int chunk = (E + P_BLOCKS - 1) / P_BLOCKS;

    // workspace: ints first, then 16B-aligned floats (~32 MB total)
    int* hist_g  = (int*)d_ws;                       // [B*P_BLOCKS] (hist, then base in-place)
    int* tot     = hist_g + (size_t)B * P_BLOCKS;    // [B]
    int* bstart  = tot + B;                          // [B+1]
    unsigned* csr = (unsigned*)(bstart + B + 1);     // [E]
    size_t ioff = ((char*)(csr + E) - (char*)d_ws + 15) & ~(size_t)15;
    float* ya  = (float*)((char*)d_ws + ioff);       // [N,8]
    float* yr  = ya + (size_t)8 * N;                 // [N,8]
    float* zl  = yr + (size_t)8 * N;                 // [N,16]
    float* zrb = zl + (size_t)16 * N;                // [N,12]

    proj1_kernel<<<2048, 256, 0, stream>>>(x, W1l, W1r, ya, yr, N);
    hist_kernel<<<P_BLOCKS, 512, 0, stream>>>(ei, E, chunk, B, hist_g);
    bsum_kernel<<<B, 256, 0, stream>>>(hist_g, tot);
    base_kernel<<<B, 256, 0, stream>>>(hist_g, tot, B, bstart);
    scatter2_kernel<<<P_BLOCKS, 512, 0, stream>>>(ei, E, chunk, B, hist_g, csr);
    agg1B_kernel<<<B, 256, 0, stream>>>(bstart, csr, ya, yr, b1l, W2l, b2l, W2r,
                                        zl, zrb, N);
    agg2B_kernel<<<B, 256, 0, stream>>>(bstart, csr, zl, zrb, out, N);
}

// Round 6
// 487.244 us; speedup vs baseline: 6.5287x; 1.0954x over previous
//
#include <hip/hip_runtime.h>
#include <hip/hip_bf16.h>
#include <math.h>

// GraphSAGE 2-layer, mean aggregation, N=100000, F=500, hid=8, classes=10.
// Project-before-aggregate + bucketed counting-sort CSR (no global atomics)
// + block-per-bucket LDS-accumulated pull aggregation, fully fused epilogues.
// Round 6: proj1 rewritten as coalesced wave-per-node-pair + shuffle reduce
// (was broadcast-load latency-bound at 40 cyc/load-instr).

#define NBKT_MAX 1600     // max buckets (N <= 102400)
#define P_BLOCKS 256      // partition blocks for hist/scatter
#define BSH 6             // bucket shift: 64 nodes/bucket
#define BSZ 64

typedef float f4v __attribute__((ext_vector_type(4)));

__device__ __forceinline__ float dot4(f4v a, f4v b) {
    return a.x * b.x + a.y * b.y + a.z * b.z + a.w * b.w;
}

// Coalesced projection: each wave handles 2 nodes per iteration.
// Lanes read x rows contiguously; W in LDS ([16][128] float4, zero-padded);
// 32 per-lane partials reduced by bisection shuffle exchange.
__global__ __launch_bounds__(256) void proj1_kernel(
    const float* __restrict__ x,
    const float* __restrict__ W1l,   // [8,500]
    const float* __restrict__ W1r,   // [8,500]
    float* __restrict__ ya,          // [N,8]  = x@W1l.T (aggregated part)
    float* __restrict__ yr,          // [N,8]  = x@W1r.T (self part)
    int N)
{
    __shared__ __align__(16) float wlds[16 * 512];   // rows padded 500->512
    for (int idx = threadIdx.x; idx < 16 * 512; idx += 256) {
        int k = idx >> 9, j = idx & 511;
        float v = 0.f;
        if (j < 500) v = (k < 8) ? W1l[k * 500 + j] : W1r[(k - 8) * 500 + j];
        wlds[idx] = v;
    }
    __syncthreads();

    const int lane = threadIdx.x & 63;
    const int wv   = threadIdx.x >> 6;
    const f4v* w4 = reinterpret_cast<const f4v*>(wlds);

    const int P = (N + 1) >> 1;                 // node pairs
    const int gw = blockIdx.x * 4 + wv;
    const int nw = gridDim.x * 4;
    const f4v zero = {0.f, 0.f, 0.f, 0.f};

    for (int p = gw; p < P; p += nw) {
        const int n0 = p * 2;
        const int n1 = min(n0 + 1, N - 1);
        const f4v* xr0 = reinterpret_cast<const f4v*>(x + (size_t)n0 * 500);
        const f4v* xr1 = reinterpret_cast<const f4v*>(x + (size_t)n1 * 500);
        // coalesced row reads: float4 index lane and lane+64 (125 float4/row)
        f4v a0 = xr0[lane];
        f4v a1 = xr1[lane];
        f4v b0 = (lane < 61) ? xr0[64 + lane] : zero;
        f4v b1 = (lane < 61) ? xr1[64 + lane] : zero;

        float acc[32];
        #pragma unroll
        for (int i = 0; i < 32; ++i) acc[i] = 0.f;

        #pragma unroll
        for (int m = 0; m < 16; ++m) {
            f4v wa = w4[m * 128 + lane];
            f4v wb = w4[m * 128 + 64 + lane];   // pad entries are zero
            acc[m]      += dot4(a0, wa) + dot4(b0, wb);
            acc[16 + m] += dot4(a1, wa) + dot4(b1, wb);
        }

        // bisection reduce: 32 values over 64 lanes
        #pragma unroll
        for (int i = 0; i < 16; ++i) {
            float keep = (lane & 1) ? acc[i + 16] : acc[i];
            float send = (lane & 1) ? acc[i]      : acc[i + 16];
            acc[i] = keep + __shfl_xor(send, 1);
        }
        #pragma unroll
        for (int i = 0; i < 8; ++i) {
            float keep = (lane & 2) ? acc[i + 8] : acc[i];
            float send = (lane & 2) ? acc[i]     : acc[i + 8];
            acc[i] = keep + __shfl_xor(send, 2);
        }
        #pragma unroll
        for (int i = 0; i < 4; ++i) {
            float keep = (lane & 4) ? acc[i + 4] : acc[i];
            float send = (lane & 4) ? acc[i]     : acc[i + 4];
            acc[i] = keep + __shfl_xor(send, 4);
        }
        #pragma unroll
        for (int i = 0; i < 2; ++i) {
            float keep = (lane & 8) ? acc[i + 2] : acc[i];
            float send = (lane & 8) ? acc[i]     : acc[i + 2];
            acc[i] = keep + __shfl_xor(send, 8);
        }
        {
            float keep = (lane & 16) ? acc[1] : acc[0];
            float send = (lane & 16) ? acc[0] : acc[1];
            acc[0] = keep + __shfl_xor(send, 16);
        }
        float tot = acc[0] + __shfl_xor(acc[0], 32);

        if (lane < 32) {
            int idx = ((lane & 1) << 4) | ((lane & 2) << 2) | (lane & 4)
                    | ((lane & 8) >> 2) | ((lane & 16) >> 4);
            int node = n0 + (idx >> 4);
            int m = idx & 15;
            if (node < N) {
                if (m < 8) ya[(size_t)node * 8 + m] = tot;
                else       yr[(size_t)node * 8 + m - 8] = tot;
            }
        }
    }
}

// Per-block LDS histogram over dst buckets (bucket = dst>>BSH).
__global__ __launch_bounds__(512) void hist_kernel(
    const int* __restrict__ ei, int E, int chunk, int B,
    int* __restrict__ hist_g)            // [B][P_BLOCKS]
{
    __shared__ int h[NBKT_MAX];
    for (int i = threadIdx.x; i < B; i += 512) h[i] = 0;
    __syncthreads();
    const int p = blockIdx.x;
    const int e0 = p * chunk, e1 = min(e0 + chunk, E);
    int e = e0 + threadIdx.x;
    for (; e + 512 < e1; e += 1024) {
        int d0 = ei[E + e], d1 = ei[E + e + 512];
        atomicAdd(&h[d0 >> BSH], 1);
        atomicAdd(&h[d1 >> BSH], 1);
    }
    for (; e < e1; e += 512) atomicAdd(&h[ei[E + e] >> BSH], 1);
    __syncthreads();
    for (int b = threadIdx.x; b < B; b += 512)
        hist_g[(size_t)b * P_BLOCKS + p] = h[b];
}

// tot[b] = sum_p hist[b][p]
__global__ __launch_bounds__(256) void bsum_kernel(
    const int* __restrict__ hist_g, int* __restrict__ tot)
{
    __shared__ int s[256];
    const int b = blockIdx.x;
    s[threadIdx.x] = hist_g[(size_t)b * P_BLOCKS + threadIdx.x];
    __syncthreads();
    for (int o = 128; o > 0; o >>= 1) {
        if (threadIdx.x < o) s[threadIdx.x] += s[threadIdx.x + o];
        __syncthreads();
    }
    if (threadIdx.x == 0) tot[b] = s[0];
}

// In-place: hist_g[b][p] <- bstart[b] + exclusive_scan_p(hist[b][p]).
__global__ __launch_bounds__(256) void base_kernel(
    int* __restrict__ hist_g, const int* __restrict__ tot, int B,
    int* __restrict__ bstart)
{
    __shared__ int sr[256];
    __shared__ int s2[256];
    __shared__ int bs_sh;
    const int b = blockIdx.x, tid = threadIdx.x;

    int part = 0;
    for (int i = tid; i < b; i += 256) part += tot[i];
    sr[tid] = part;
    __syncthreads();
    for (int o = 128; o > 0; o >>= 1) {
        if (tid < o) sr[tid] += sr[tid + o];
        __syncthreads();
    }
    if (tid == 0) bs_sh = sr[0];
    __syncthreads();
    const int bs = bs_sh;

    const int v = hist_g[(size_t)b * P_BLOCKS + tid];
    s2[tid] = v;
    __syncthreads();
    for (int o = 1; o < 256; o <<= 1) {
        int t = (tid >= o) ? s2[tid - o] : 0;
        __syncthreads();
        s2[tid] += t;
        __syncthreads();
    }
    hist_g[(size_t)b * P_BLOCKS + tid] = bs + s2[tid] - v;   // exclusive base
    if (tid == 0) bstart[b] = bs;
    if (b == B - 1 && tid == 255) bstart[B] = bs + s2[255];
}

// Scatter packed (src | dstLow<<17) into bucket-partitioned csr using LDS cursors.
__global__ __launch_bounds__(512) void scatter2_kernel(
    const int* __restrict__ ei, int E, int chunk, int B,
    const int* __restrict__ base, unsigned* __restrict__ csr)
{
    __shared__ int cur[NBKT_MAX];
    const int p = blockIdx.x;
    for (int b = threadIdx.x; b < B; b += 512) cur[b] = base[(size_t)b * P_BLOCKS + p];
    __syncthreads();
    const int e0 = p * chunk, e1 = min(e0 + chunk, E);
    int e = e0 + threadIdx.x;
    for (; e + 512 < e1; e += 1024) {
        int s0 = ei[e],     s1 = ei[e + 512];
        int d0 = ei[E + e], d1 = ei[E + e + 512];
        int p0 = atomicAdd(&cur[d0 >> BSH], 1);
        int p1 = atomicAdd(&cur[d1 >> BSH], 1);
        csr[p0] = (unsigned)s0 | ((unsigned)(d0 & (BSZ - 1)) << 17);
        csr[p1] = (unsigned)s1 | ((unsigned)(d1 & (BSZ - 1)) << 17);
    }
    for (; e < e1; e += 512) {
        int s0 = ei[e], d0 = ei[E + e];
        int p0 = atomicAdd(&cur[d0 >> BSH], 1);
        csr[p0] = (unsigned)s0 | ((unsigned)(d0 & (BSZ - 1)) << 17);
    }
}

// Layer-1 aggregation: 2 lanes per edge (32B row of ya), LDS accumulate,
// fused mean + bias + self + ELU + both layer-2 projections.
__global__ __launch_bounds__(256) void agg1B_kernel(
    const int* __restrict__ bstart,
    const unsigned* __restrict__ csr,
    const float* __restrict__ ya,    // [N,8]
    const float* __restrict__ yr,    // [N,8]
    const float* __restrict__ b1,    // [8]
    const float* __restrict__ W2l,   // [10,8]
    const float* __restrict__ b2,    // [10]
    const float* __restrict__ W2r,   // [10,8]
    float* __restrict__ zl,          // [N,16] padded, 64B rows
    float* __restrict__ zrb,         // [N,12]  (col10 = invdeg)
    int N)
{
    __shared__ float acc[BSZ * 9];
    __shared__ int   cnt[BSZ];
    __shared__ float wb[178];        // b1[8] | W2l[80] | b2[10] | W2r[80]
    const int tid = threadIdx.x;
    for (int i = tid; i < BSZ * 9; i += 256) acc[i] = 0.f;
    if (tid < BSZ) cnt[tid] = 0;
    if (tid < 178)
        wb[tid] = (tid < 8) ? b1[tid] : (tid < 88) ? W2l[tid - 8]
                 : (tid < 98) ? b2[tid - 88] : W2r[tid - 98];
    __syncthreads();

    const int b = blockIdx.x;
    const int e0 = bstart[b], e1 = bstart[b + 1];
    const f4v* ya4 = reinterpret_cast<const f4v*>(ya);
    const int q = tid & 1;
    int e = e0 + (tid >> 1);
    for (; e + 128 < e1; e += 256) {
        unsigned pk0 = csr[e], pk1 = csr[e + 128];
        f4v v0 = __builtin_nontemporal_load(&ya4[(size_t)(pk0 & 0x1FFFFu) * 2 + q]);
        f4v v1 = __builtin_nontemporal_load(&ya4[(size_t)(pk1 & 0x1FFFFu) * 2 + q]);
        int dl0 = pk0 >> 17, dl1 = pk1 >> 17;
        float* A0 = acc + dl0 * 9 + q * 4;
        float* A1 = acc + dl1 * 9 + q * 4;
        atomicAdd(A0 + 0, v0.x); atomicAdd(A0 + 1, v0.y);
        atomicAdd(A0 + 2, v0.z); atomicAdd(A0 + 3, v0.w);
        atomicAdd(A1 + 0, v1.x); atomicAdd(A1 + 1, v1.y);
        atomicAdd(A1 + 2, v1.z); atomicAdd(A1 + 3, v1.w);
        if (q == 0) { atomicAdd(&cnt[dl0], 1); atomicAdd(&cnt[dl1], 1); }
    }
    for (; e < e1; e += 128) {
        unsigned pk0 = csr[e];
        f4v v0 = __builtin_nontemporal_load(&ya4[(size_t)(pk0 & 0x1FFFFu) * 2 + q]);
        int dl0 = pk0 >> 17;
        float* A0 = acc + dl0 * 9 + q * 4;
        atomicAdd(A0 + 0, v0.x); atomicAdd(A0 + 1, v0.y);
        atomicAdd(A0 + 2, v0.z); atomicAdd(A0 + 3, v0.w);
        if (q == 0) atomicAdd(&cnt[dl0], 1);
    }
    __syncthreads();

    if (tid >= BSZ) return;
    const int node = b * BSZ + tid;
    if (node >= N) return;
    const float inv = 1.f / fmaxf((float)cnt[tid], 1.f);
    const float* rrp = yr + (size_t)node * 8;
    const float* A = acc + tid * 9;

    float h[8];
    #pragma unroll
    for (int t = 0; t < 8; ++t) {
        float v = A[t] * inv + wb[t] + rrp[t];
        h[t] = v > 0.f ? v : expm1f(v);   // ELU(alpha=1)
    }

    float zlv[10], zrv[10];
    #pragma unroll
    for (int k = 0; k < 10; ++k) {
        float al = 0.f, ar = wb[88 + k];
        #pragma unroll
        for (int t = 0; t < 8; ++t) {
            al += wb[8 + k * 8 + t]  * h[t];
            ar += wb[98 + k * 8 + t] * h[t];
        }
        zlv[k] = al; zrv[k] = ar;
    }

    float4* zl4w = reinterpret_cast<float4*>(zl + (size_t)node * 16);
    zl4w[0] = make_float4(zlv[0], zlv[1], zlv[2], zlv[3]);
    zl4w[1] = make_float4(zlv[4], zlv[5], zlv[6], zlv[7]);
    zl4w[2] = make_float4(zlv[8], zlv[9], 0.f, 0.f);
    zl4w[3] = make_float4(0.f, 0.f, 0.f, 0.f);
    float4* zr4w = reinterpret_cast<float4*>(zrb + (size_t)node * 12);
    zr4w[0] = make_float4(zrv[0], zrv[1], zrv[2], zrv[3]);
    zr4w[1] = make_float4(zrv[4], zrv[5], zrv[6], zrv[7]);
    zr4w[2] = make_float4(zrv[8], zrv[9], inv, 0.f);   // col10 = invdeg
}

// Layer-2 aggregation: 4 lanes per edge (64B-aligned zl row, q<3 active),
// fused mean + r-branch + log-softmax.
__global__ __launch_bounds__(256) void agg2B_kernel(
    const int* __restrict__ bstart,
    const unsigned* __restrict__ csr,
    const float* __restrict__ zl,    // [N,16]
    const float* __restrict__ zrb,   // [N,12] (col10 = invdeg)
    float* __restrict__ out,         // [N,10]
    int N)
{
    __shared__ float acc[BSZ * 17];
    const int tid = threadIdx.x;
    for (int i = tid; i < BSZ * 17; i += 256) acc[i] = 0.f;
    __syncthreads();

    const int b = blockIdx.x;
    const int e0 = bstart[b], e1 = bstart[b + 1];
    const f4v* zl4 = reinterpret_cast<const f4v*>(zl);
    const int q = tid & 3;
    if (q < 3) {
        int e = e0 + (tid >> 2);
        for (; e + 64 < e1; e += 128) {
            unsigned pk0 = csr[e], pk1 = csr[e + 64];
            f4v v0 = __builtin_nontemporal_load(&zl4[(size_t)(pk0 & 0x1FFFFu) * 4 + q]);
            f4v v1 = __builtin_nontemporal_load(&zl4[(size_t)(pk1 & 0x1FFFFu) * 4 + q]);
            int dl0 = pk0 >> 17, dl1 = pk1 >> 17;
            float* A0 = acc + dl0 * 17 + q * 4;
            float* A1 = acc + dl1 * 17 + q * 4;
            if (q < 2) {
                atomicAdd(A0 + 0, v0.x); atomicAdd(A0 + 1, v0.y);
                atomicAdd(A0 + 2, v0.z); atomicAdd(A0 + 3, v0.w);
                atomicAdd(A1 + 0, v1.x); atomicAdd(A1 + 1, v1.y);
                atomicAdd(A1 + 2, v1.z); atomicAdd(A1 + 3, v1.w);
            } else {
                atomicAdd(A0 + 0, v0.x); atomicAdd(A0 + 1, v0.y);
                atomicAdd(A1 + 0, v1.x); atomicAdd(A1 + 1, v1.y);
            }
        }
        for (; e < e1; e += 64) {
            unsigned pk0 = csr[e];
            f4v v0 = __builtin_nontemporal_load(&zl4[(size_t)(pk0 & 0x1FFFFu) * 4 + q]);
            int dl0 = pk0 >> 17;
            float* A0 = acc + dl0 * 17 + q * 4;
            if (q < 2) {
                atomicAdd(A0 + 0, v0.x); atomicAdd(A0 + 1, v0.y);
                atomicAdd(A0 + 2, v0.z); atomicAdd(A0 + 3, v0.w);
            } else {
                atomicAdd(A0 + 0, v0.x); atomicAdd(A0 + 1, v0.y);
            }
        }
    }
    __syncthreads();

    if (tid >= BSZ) return;
    const int node = b * BSZ + tid;
    if (node >= N) return;
    const float* zr = zrb + (size_t)node * 12;
    const float inv = zr[10];
    const float* A = acc + tid * 17;
    float v[10];
    float mx = -1e30f;
    #pragma unroll
    for (int k = 0; k < 10; ++k) {
        v[k] = A[k] * inv + zr[k];
        mx = fmaxf(mx, v[k]);
    }
    float ssum = 0.f;
    #pragma unroll
    for (int k = 0; k < 10; ++k) ssum += expf(v[k] - mx);
    const float lse = mx + logf(ssum);
    float2* o = reinterpret_cast<float2*>(out + (size_t)node * 10);
    o[0] = make_float2(v[0] - lse, v[1] - lse);
    o[1] = make_float2(v[2] - lse, v[3] - lse);
    o[2] = make_float2(v[4] - lse, v[5] - lse);
    o[3] = make_float2(v[6] - lse, v[7] - lse);
    o[4] = make_float2(v[8] - lse, v[9] - lse);
}

extern "C" void kernel_launch(void* const* d_in, const int* in_sizes, int n_in,
                              void* d_out, int out_size, void* d_ws, size_t ws_size,
                              hipStream_t stream) {
    const float* x   = (const float*)d_in[0];
    const int*   ei  = (const int*)d_in[1];
    const float* W1l = (const float*)d_in[2];
    const float* b1l = (const float*)d_in[3];
    const float* W1r = (const float*)d_in[4];
    const float* W2l = (const float*)d_in[5];
    const float* b2l = (const float*)d_in[6];
    const float* W2r = (const float*)d_in[7];
    float* out = (float*)d_out;

    const int N = in_sizes[0] / 500;
    const int E = in_sizes[1] / 2;
    const int B = (N + BSZ - 1) >> BSH;       // buckets of BSZ nodes
    const int chunk = (E + P_BLOCKS - 1) / P_BLOCKS;

    // workspace: ints first, then 16B-aligned floats (~32 MB total)
    int* hist_g  = (int*)d_ws;                       // [B*P_BLOCKS] (hist, then base in-place)
    int* tot     = hist_g + (size_t)B * P_BLOCKS;    // [B]
    int* bstart  = tot + B;                          // [B+1]
    unsigned* csr = (unsigned*)(bstart + B + 1);     // [E]
    size_t ioff = ((char*)(csr + E) - (char*)d_ws + 15) & ~(size_t)15;
    float* ya  = (float*)((char*)d_ws + ioff);       // [N,8]
    float* yr  = ya + (size_t)8 * N;                 // [N,8]
    float* zl  = yr + (size_t)8 * N;                 // [N,16]
    float* zrb = zl + (size_t)16 * N;                // [N,12]

    proj1_kernel<<<1280, 256, 0, stream>>>(x, W1l, W1r, ya, yr, N);
    hist_kernel<<<P_BLOCKS, 512, 0, stream>>>(ei, E, chunk, B, hist_g);
    bsum_kernel<<<B, 256, 0, stream>>>(hist_g, tot);
    base_kernel<<<B, 256, 0, stream>>>(hist_g, tot, B, bstart);
    scatter2_kernel<<<P_BLOCKS, 512, 0, stream>>>(ei, E, chunk, B, hist_g, csr);
    agg1B_kernel<<<B, 256, 0, stream>>>(bstart, csr, ya, yr, b1l, W2l, b2l, W2r,
                                        zl, zrb, N);
    agg2B_kernel<<<B, 256, 0, stream>>>(bstart, csr, zl, zrb, out, N);
}

// Round 7
// 486.999 us; speedup vs baseline: 6.5320x; 1.0005x over previous
//
#include <hip/hip_runtime.h>
#include <hip/hip_bf16.h>
#include <math.h>

// GraphSAGE 2-layer, mean aggregation, N=100000, F=500, hid=8, classes=10.
// Project-before-aggregate + bucketed counting-sort CSR (no global atomics)
// + block-per-bucket LDS-accumulated pull aggregation, fully fused epilogues.
// Round 7: plain (cached) gather loads — round-6 NT loads killed L2/L3 reuse
// (FETCH 65->185 MB, one HBM line per edge). Chunked gathers kept.

#define NBKT_MAX 1600     // max buckets (N <= 102400)
#define P_BLOCKS 256      // partition blocks for hist/scatter
#define BSH 6             // bucket shift: 64 nodes/bucket
#define BSZ 64

typedef float f4v __attribute__((ext_vector_type(4)));

__device__ __forceinline__ float dot4(f4v a, f4v b) {
    return a.x * b.x + a.y * b.y + a.z * b.z + a.w * b.w;
}

// Coalesced projection: each wave handles 2 nodes per iteration.
// Lanes read x rows contiguously; W in LDS ([16][128] float4, zero-padded);
// 32 per-lane partials reduced by bisection shuffle exchange.
__global__ __launch_bounds__(256) void proj1_kernel(
    const float* __restrict__ x,
    const float* __restrict__ W1l,   // [8,500]
    const float* __restrict__ W1r,   // [8,500]
    float* __restrict__ ya,          // [N,8]  = x@W1l.T (aggregated part)
    float* __restrict__ yr,          // [N,8]  = x@W1r.T (self part)
    int N)
{
    __shared__ __align__(16) float wlds[16 * 512];   // rows padded 500->512
    for (int idx = threadIdx.x; idx < 16 * 512; idx += 256) {
        int k = idx >> 9, j = idx & 511;
        float v = 0.f;
        if (j < 500) v = (k < 8) ? W1l[k * 500 + j] : W1r[(k - 8) * 500 + j];
        wlds[idx] = v;
    }
    __syncthreads();

    const int lane = threadIdx.x & 63;
    const int wv   = threadIdx.x >> 6;
    const f4v* w4 = reinterpret_cast<const f4v*>(wlds);

    const int P = (N + 1) >> 1;                 // node pairs
    const int gw = blockIdx.x * 4 + wv;
    const int nw = gridDim.x * 4;
    const f4v zero = {0.f, 0.f, 0.f, 0.f};

    for (int p = gw; p < P; p += nw) {
        const int n0 = p * 2;
        const int n1 = min(n0 + 1, N - 1);
        const f4v* xr0 = reinterpret_cast<const f4v*>(x + (size_t)n0 * 500);
        const f4v* xr1 = reinterpret_cast<const f4v*>(x + (size_t)n1 * 500);
        // coalesced row reads: float4 index lane and lane+64 (125 float4/row)
        f4v a0 = xr0[lane];
        f4v a1 = xr1[lane];
        f4v b0 = (lane < 61) ? xr0[64 + lane] : zero;
        f4v b1 = (lane < 61) ? xr1[64 + lane] : zero;

        float acc[32];
        #pragma unroll
        for (int i = 0; i < 32; ++i) acc[i] = 0.f;

        #pragma unroll
        for (int m = 0; m < 16; ++m) {
            f4v wa = w4[m * 128 + lane];
            f4v wb = w4[m * 128 + 64 + lane];   // pad entries are zero
            acc[m]      += dot4(a0, wa) + dot4(b0, wb);
            acc[16 + m] += dot4(a1, wa) + dot4(b1, wb);
        }

        // bisection reduce: 32 values over 64 lanes
        #pragma unroll
        for (int i = 0; i < 16; ++i) {
            float keep = (lane & 1) ? acc[i + 16] : acc[i];
            float send = (lane & 1) ? acc[i]      : acc[i + 16];
            acc[i] = keep + __shfl_xor(send, 1);
        }
        #pragma unroll
        for (int i = 0; i < 8; ++i) {
            float keep = (lane & 2) ? acc[i + 8] : acc[i];
            float send = (lane & 2) ? acc[i]     : acc[i + 8];
            acc[i] = keep + __shfl_xor(send, 2);
        }
        #pragma unroll
        for (int i = 0; i < 4; ++i) {
            float keep = (lane & 4) ? acc[i + 4] : acc[i];
            float send = (lane & 4) ? acc[i]     : acc[i + 4];
            acc[i] = keep + __shfl_xor(send, 4);
        }
        #pragma unroll
        for (int i = 0; i < 2; ++i) {
            float keep = (lane & 8) ? acc[i + 2] : acc[i];
            float send = (lane & 8) ? acc[i]     : acc[i + 2];
            acc[i] = keep + __shfl_xor(send, 8);
        }
        {
            float keep = (lane & 16) ? acc[1] : acc[0];
            float send = (lane & 16) ? acc[0] : acc[1];
            acc[0] = keep + __shfl_xor(send, 16);
        }
        float tot = acc[0] + __shfl_xor(acc[0], 32);

        if (lane < 32) {
            int idx = ((lane & 1) << 4) | ((lane & 2) << 2) | (lane & 4)
                    | ((lane & 8) >> 2) | ((lane & 16) >> 4);
            int node = n0 + (idx >> 4);
            int m = idx & 15;
            if (node < N) {
                if (m < 8) ya[(size_t)node * 8 + m] = tot;
                else       yr[(size_t)node * 8 + m - 8] = tot;
            }
        }
    }
}

// Per-block LDS histogram over dst buckets (bucket = dst>>BSH).
__global__ __launch_bounds__(512) void hist_kernel(
    const int* __restrict__ ei, int E, int chunk, int B,
    int* __restrict__ hist_g)            // [B][P_BLOCKS]
{
    __shared__ int h[NBKT_MAX];
    for (int i = threadIdx.x; i < B; i += 512) h[i] = 0;
    __syncthreads();
    const int p = blockIdx.x;
    const int e0 = p * chunk, e1 = min(e0 + chunk, E);
    int e = e0 + threadIdx.x;
    for (; e + 512 < e1; e += 1024) {
        int d0 = ei[E + e], d1 = ei[E + e + 512];
        atomicAdd(&h[d0 >> BSH], 1);
        atomicAdd(&h[d1 >> BSH], 1);
    }
    for (; e < e1; e += 512) atomicAdd(&h[ei[E + e] >> BSH], 1);
    __syncthreads();
    for (int b = threadIdx.x; b < B; b += 512)
        hist_g[(size_t)b * P_BLOCKS + p] = h[b];
}

// tot[b] = sum_p hist[b][p]
__global__ __launch_bounds__(256) void bsum_kernel(
    const int* __restrict__ hist_g, int* __restrict__ tot)
{
    __shared__ int s[256];
    const int b = blockIdx.x;
    s[threadIdx.x] = hist_g[(size_t)b * P_BLOCKS + threadIdx.x];
    __syncthreads();
    for (int o = 128; o > 0; o >>= 1) {
        if (threadIdx.x < o) s[threadIdx.x] += s[threadIdx.x + o];
        __syncthreads();
    }
    if (threadIdx.x == 0) tot[b] = s[0];
}

// In-place: hist_g[b][p] <- bstart[b] + exclusive_scan_p(hist[b][p]).
__global__ __launch_bounds__(256) void base_kernel(
    int* __restrict__ hist_g, const int* __restrict__ tot, int B,
    int* __restrict__ bstart)
{
    __shared__ int sr[256];
    __shared__ int s2[256];
    __shared__ int bs_sh;
    const int b = blockIdx.x, tid = threadIdx.x;

    int part = 0;
    for (int i = tid; i < b; i += 256) part += tot[i];
    sr[tid] = part;
    __syncthreads();
    for (int o = 128; o > 0; o >>= 1) {
        if (tid < o) sr[tid] += sr[tid + o];
        __syncthreads();
    }
    if (tid == 0) bs_sh = sr[0];
    __syncthreads();
    const int bs = bs_sh;

    const int v = hist_g[(size_t)b * P_BLOCKS + tid];
    s2[tid] = v;
    __syncthreads();
    for (int o = 1; o < 256; o <<= 1) {
        int t = (tid >= o) ? s2[tid - o] : 0;
        __syncthreads();
        s2[tid] += t;
        __syncthreads();
    }
    hist_g[(size_t)b * P_BLOCKS + tid] = bs + s2[tid] - v;   // exclusive base
    if (tid == 0) bstart[b] = bs;
    if (b == B - 1 && tid == 255) bstart[B] = bs + s2[255];
}

// Scatter packed (src | dstLow<<17) into bucket-partitioned csr using LDS cursors.
__global__ __launch_bounds__(512) void scatter2_kernel(
    const int* __restrict__ ei, int E, int chunk, int B,
    const int* __restrict__ base, unsigned* __restrict__ csr)
{
    __shared__ int cur[NBKT_MAX];
    const int p = blockIdx.x;
    for (int b = threadIdx.x; b < B; b += 512) cur[b] = base[(size_t)b * P_BLOCKS + p];
    __syncthreads();
    const int e0 = p * chunk, e1 = min(e0 + chunk, E);
    int e = e0 + threadIdx.x;
    for (; e + 512 < e1; e += 1024) {
        int s0 = ei[e],     s1 = ei[e + 512];
        int d0 = ei[E + e], d1 = ei[E + e + 512];
        int p0 = atomicAdd(&cur[d0 >> BSH], 1);
        int p1 = atomicAdd(&cur[d1 >> BSH], 1);
        csr[p0] = (unsigned)s0 | ((unsigned)(d0 & (BSZ - 1)) << 17);
        csr[p1] = (unsigned)s1 | ((unsigned)(d1 & (BSZ - 1)) << 17);
    }
    for (; e < e1; e += 512) {
        int s0 = ei[e], d0 = ei[E + e];
        int p0 = atomicAdd(&cur[d0 >> BSH], 1);
        csr[p0] = (unsigned)s0 | ((unsigned)(d0 & (BSZ - 1)) << 17);
    }
}

// Layer-1 aggregation: 2 lanes per edge (32B row of ya), LDS accumulate,
// fused mean + bias + self + ELU + both layer-2 projections.
__global__ __launch_bounds__(256) void agg1B_kernel(
    const int* __restrict__ bstart,
    const unsigned* __restrict__ csr,
    const float* __restrict__ ya,    // [N,8]
    const float* __restrict__ yr,    // [N,8]
    const float* __restrict__ b1,    // [8]
    const float* __restrict__ W2l,   // [10,8]
    const float* __restrict__ b2,    // [10]
    const float* __restrict__ W2r,   // [10,8]
    float* __restrict__ zl,          // [N,16] padded, 64B rows
    float* __restrict__ zrb,         // [N,12]  (col10 = invdeg)
    int N)
{
    __shared__ float acc[BSZ * 9];
    __shared__ int   cnt[BSZ];
    __shared__ float wb[178];        // b1[8] | W2l[80] | b2[10] | W2r[80]
    const int tid = threadIdx.x;
    for (int i = tid; i < BSZ * 9; i += 256) acc[i] = 0.f;
    if (tid < BSZ) cnt[tid] = 0;
    if (tid < 178)
        wb[tid] = (tid < 8) ? b1[tid] : (tid < 88) ? W2l[tid - 8]
                 : (tid < 98) ? b2[tid - 88] : W2r[tid - 98];
    __syncthreads();

    const int b = blockIdx.x;
    const int e0 = bstart[b], e1 = bstart[b + 1];
    const f4v* ya4 = reinterpret_cast<const f4v*>(ya);
    const int q = tid & 1;
    int e = e0 + (tid >> 1);
    for (; e + 128 < e1; e += 256) {
        unsigned pk0 = csr[e], pk1 = csr[e + 128];
        f4v v0 = ya4[(size_t)(pk0 & 0x1FFFFu) * 2 + q];
        f4v v1 = ya4[(size_t)(pk1 & 0x1FFFFu) * 2 + q];
        int dl0 = pk0 >> 17, dl1 = pk1 >> 17;
        float* A0 = acc + dl0 * 9 + q * 4;
        float* A1 = acc + dl1 * 9 + q * 4;
        atomicAdd(A0 + 0, v0.x); atomicAdd(A0 + 1, v0.y);
        atomicAdd(A0 + 2, v0.z); atomicAdd(A0 + 3, v0.w);
        atomicAdd(A1 + 0, v1.x); atomicAdd(A1 + 1, v1.y);
        atomicAdd(A1 + 2, v1.z); atomicAdd(A1 + 3, v1.w);
        if (q == 0) { atomicAdd(&cnt[dl0], 1); atomicAdd(&cnt[dl1], 1); }
    }
    for (; e < e1; e += 128) {
        unsigned pk0 = csr[e];
        f4v v0 = ya4[(size_t)(pk0 & 0x1FFFFu) * 2 + q];
        int dl0 = pk0 >> 17;
        float* A0 = acc + dl0 * 9 + q * 4;
        atomicAdd(A0 + 0, v0.x); atomicAdd(A0 + 1, v0.y);
        atomicAdd(A0 + 2, v0.z); atomicAdd(A0 + 3, v0.w);
        if (q == 0) atomicAdd(&cnt[dl0], 1);
    }
    __syncthreads();

    if (tid >= BSZ) return;
    const int node = b * BSZ + tid;
    if (node >= N) return;
    const float inv = 1.f / fmaxf((float)cnt[tid], 1.f);
    const float* rrp = yr + (size_t)node * 8;
    const float* A = acc + tid * 9;

    float h[8];
    #pragma unroll
    for (int t = 0; t < 8; ++t) {
        float v = A[t] * inv + wb[t] + rrp[t];
        h[t] = v > 0.f ? v : expm1f(v);   // ELU(alpha=1)
    }

    float zlv[10], zrv[10];
    #pragma unroll
    for (int k = 0; k < 10; ++k) {
        float al = 0.f, ar = wb[88 + k];
        #pragma unroll
        for (int t = 0; t < 8; ++t) {
            al += wb[8 + k * 8 + t]  * h[t];
            ar += wb[98 + k * 8 + t] * h[t];
        }
        zlv[k] = al; zrv[k] = ar;
    }

    float4* zl4w = reinterpret_cast<float4*>(zl + (size_t)node * 16);
    zl4w[0] = make_float4(zlv[0], zlv[1], zlv[2], zlv[3]);
    zl4w[1] = make_float4(zlv[4], zlv[5], zlv[6], zlv[7]);
    zl4w[2] = make_float4(zlv[8], zlv[9], 0.f, 0.f);
    zl4w[3] = make_float4(0.f, 0.f, 0.f, 0.f);
    float4* zr4w = reinterpret_cast<float4*>(zrb + (size_t)node * 12);
    zr4w[0] = make_float4(zrv[0], zrv[1], zrv[2], zrv[3]);
    zr4w[1] = make_float4(zrv[4], zrv[5], zrv[6], zrv[7]);
    zr4w[2] = make_float4(zrv[8], zrv[9], inv, 0.f);   // col10 = invdeg
}

// Layer-2 aggregation: 4 lanes per edge (64B-aligned zl row, q<3 active),
// fused mean + r-branch + log-softmax.
__global__ __launch_bounds__(256) void agg2B_kernel(
    const int* __restrict__ bstart,
    const unsigned* __restrict__ csr,
    const float* __restrict__ zl,    // [N,16]
    const float* __restrict__ zrb,   // [N,12] (col10 = invdeg)
    float* __restrict__ out,         // [N,10]
    int N)
{
    __shared__ float acc[BSZ * 17];
    const int tid = threadIdx.x;
    for (int i = tid; i < BSZ * 17; i += 256) acc[i] = 0.f;
    __syncthreads();

    const int b = blockIdx.x;
    const int e0 = bstart[b], e1 = bstart[b + 1];
    const f4v* zl4 = reinterpret_cast<const f4v*>(zl);
    const int q = tid & 3;
    if (q < 3) {
        int e = e0 + (tid >> 2);
        for (; e + 64 < e1; e += 128) {
            unsigned pk0 = csr[e], pk1 = csr[e + 64];
            f4v v0 = zl4[(size_t)(pk0 & 0x1FFFFu) * 4 + q];
            f4v v1 = zl4[(size_t)(pk1 & 0x1FFFFu) * 4 + q];
            int dl0 = pk0 >> 17, dl1 = pk1 >> 17;
            float* A0 = acc + dl0 * 17 + q * 4;
            float* A1 = acc + dl1 * 17 + q * 4;
            if (q < 2) {
                atomicAdd(A0 + 0, v0.x); atomicAdd(A0 + 1, v0.y);
                atomicAdd(A0 + 2, v0.z); atomicAdd(A0 + 3, v0.w);
                atomicAdd(A1 + 0, v1.x); atomicAdd(A1 + 1, v1.y);
                atomicAdd(A1 + 2, v1.z); atomicAdd(A1 + 3, v1.w);
            } else {
                atomicAdd(A0 + 0, v0.x); atomicAdd(A0 + 1, v0.y);
                atomicAdd(A1 + 0, v1.x); atomicAdd(A1 + 1, v1.y);
            }
        }
        for (; e < e1; e += 64) {
            unsigned pk0 = csr[e];
            f4v v0 = zl4[(size_t)(pk0 & 0x1FFFFu) * 4 + q];
            int dl0 = pk0 >> 17;
            float* A0 = acc + dl0 * 17 + q * 4;
            if (q < 2) {
                atomicAdd(A0 + 0, v0.x); atomicAdd(A0 + 1, v0.y);
                atomicAdd(A0 + 2, v0.z); atomicAdd(A0 + 3, v0.w);
            } else {
                atomicAdd(A0 + 0, v0.x); atomicAdd(A0 + 1, v0.y);
            }
        }
    }
    __syncthreads();

    if (tid >= BSZ) return;
    const int node = b * BSZ + tid;
    if (node >= N) return;
    const float* zr = zrb + (size_t)node * 12;
    const float inv = zr[10];
    const float* A = acc + tid * 17;
    float v[10];
    float mx = -1e30f;
    #pragma unroll
    for (int k = 0; k < 10; ++k) {
        v[k] = A[k] * inv + zr[k];
        mx = fmaxf(mx, v[k]);
    }
    float ssum = 0.f;
    #pragma unroll
    for (int k = 0; k < 10; ++k) ssum += expf(v[k] - mx);
    const float lse = mx + logf(ssum);
    float2* o = reinterpret_cast<float2*>(out + (size_t)node * 10);
    o[0] = make_float2(v[0] - lse, v[1] - lse);
    o[1] = make_float2(v[2] - lse, v[3] - lse);
    o[2] = make_float2(v[4] - lse, v[5] - lse);
    o[3] = make_float2(v[6] - lse, v[7] - lse);
    o[4] = make_float2(v[8] - lse, v[9] - lse);
}

extern "C" void kernel_launch(void* const* d_in, const int* in_sizes, int n_in,
                              void* d_out, int out_size, void* d_ws, size_t ws_size,
                              hipStream_t stream) {
    const float* x   = (const float*)d_in[0];
    const int*   ei  = (const int*)d_in[1];
    const float* W1l = (const float*)d_in[2];
    const float* b1l = (const float*)d_in[3];
    const float* W1r = (const float*)d_in[4];
    const float* W2l = (const float*)d_in[5];
    const float* b2l = (const float*)d_in[6];
    const float* W2r = (const float*)d_in[7];
    float* out = (float*)d_out;

    const int N = in_sizes[0] / 500;
    const int E = in_sizes[1] / 2;
    const int B = (N + BSZ - 1) >> BSH;       // buckets of BSZ nodes
    const int chunk = (E + P_BLOCKS - 1) / P_BLOCKS;

    // workspace: ints first, then 16B-aligned floats (~32 MB total)
    int* hist_g  = (int*)d_ws;                       // [B*P_BLOCKS] (hist, then base in-place)
    int* tot     = hist_g + (size_t)B * P_BLOCKS;    // [B]
    int* bstart  = tot + B;                          // [B+1]
    unsigned* csr = (unsigned*)(bstart + B + 1);     // [E]
    size_t ioff = ((char*)(csr + E) - (char*)d_ws + 15) & ~(size_t)15;
    float* ya  = (float*)((char*)d_ws + ioff);       // [N,8]
    float* yr  = ya + (size_t)8 * N;                 // [N,8]
    float* zl  = yr + (size_t)8 * N;                 // [N,16]
    float* zrb = zl + (size_t)16 * N;                // [N,12]

    proj1_kernel<<<1280, 256, 0, stream>>>(x, W1l, W1r, ya, yr, N);
    hist_kernel<<<P_BLOCKS, 512, 0, stream>>>(ei, E, chunk, B, hist_g);
    bsum_kernel<<<B, 256, 0, stream>>>(hist_g, tot);
    base_kernel<<<B, 256, 0, stream>>>(hist_g, tot, B, bstart);
    scatter2_kernel<<<P_BLOCKS, 512, 0, stream>>>(ei, E, chunk, B, hist_g, csr);
    agg1B_kernel<<<B, 256, 0, stream>>>(bstart, csr, ya, yr, b1l, W2l, b2l, W2r,
                                        zl, zrb, N);
    agg2B_kernel<<<B, 256, 0, stream>>>(bstart, csr, zl, zrb, out, N);
}

// Round 8
// 486.597 us; speedup vs baseline: 6.5374x; 1.0008x over previous
//
#include <hip/hip_runtime.h>
#include <hip/hip_bf16.h>
#include <math.h>

// GraphSAGE 2-layer, mean aggregation, N=100000, F=500, hid=8, classes=10.
// Project-before-aggregate + bucketed counting-sort CSR (no global atomics)
// + block-per-bucket LDS-accumulated pull aggregation, fully fused epilogues.
// Round 8: bf16 gather tables (ya 16B rows, zl 32B rows) so both fit in a
// 4 MB per-XCD L2 -> random gathers become L2 hits. (R4/6/7 showed ~190 us
// regardless of HBM traffic: random-line bound on a >4MB table.)
// LDS accumulation stays f32; only gathered values are bf16-rounded.

#define NBKT_MAX 1600     // max buckets (N <= 102400)
#define P_BLOCKS 256      // partition blocks for hist/scatter
#define BSH 6             // bucket shift: 64 nodes/bucket
#define BSZ 64

typedef float f4v __attribute__((ext_vector_type(4)));

__device__ __forceinline__ float dot4(f4v a, f4v b) {
    return a.x * b.x + a.y * b.y + a.z * b.z + a.w * b.w;
}
__device__ __forceinline__ unsigned f2bf(float f) {   // RNE f32->bf16 bits
    unsigned u = __float_as_uint(f);
    return (u + 0x7FFFu + ((u >> 16) & 1u)) >> 16;
}
__device__ __forceinline__ float bflo(unsigned w) { return __uint_as_float(w << 16); }
__device__ __forceinline__ float bfhi(unsigned w) { return __uint_as_float(w & 0xFFFF0000u); }

// Coalesced projection: each wave handles 2 nodes per iteration.
// ya written as bf16 (16B rows), yr kept f32 (read once, per-node).
__global__ __launch_bounds__(256) void proj1_kernel(
    const float* __restrict__ x,
    const float* __restrict__ W1l,   // [8,500]
    const float* __restrict__ W1r,   // [8,500]
    unsigned short* __restrict__ yab, // [N,8] bf16 = x@W1l.T (aggregated part)
    float* __restrict__ yr,           // [N,8] f32  = x@W1r.T (self part)
    int N)
{
    __shared__ __align__(16) float wlds[16 * 512];   // rows padded 500->512
    for (int idx = threadIdx.x; idx < 16 * 512; idx += 256) {
        int k = idx >> 9, j = idx & 511;
        float v = 0.f;
        if (j < 500) v = (k < 8) ? W1l[k * 500 + j] : W1r[(k - 8) * 500 + j];
        wlds[idx] = v;
    }
    __syncthreads();

    const int lane = threadIdx.x & 63;
    const int wv   = threadIdx.x >> 6;
    const f4v* w4 = reinterpret_cast<const f4v*>(wlds);

    const int P = (N + 1) >> 1;                 // node pairs
    const int gw = blockIdx.x * 4 + wv;
    const int nw = gridDim.x * 4;
    const f4v zero = {0.f, 0.f, 0.f, 0.f};

    for (int p = gw; p < P; p += nw) {
        const int n0 = p * 2;
        const int n1 = min(n0 + 1, N - 1);
        const f4v* xr0 = reinterpret_cast<const f4v*>(x + (size_t)n0 * 500);
        const f4v* xr1 = reinterpret_cast<const f4v*>(x + (size_t)n1 * 500);
        f4v a0 = xr0[lane];
        f4v a1 = xr1[lane];
        f4v b0 = (lane < 61) ? xr0[64 + lane] : zero;
        f4v b1 = (lane < 61) ? xr1[64 + lane] : zero;

        float acc[32];
        #pragma unroll
        for (int i = 0; i < 32; ++i) acc[i] = 0.f;

        #pragma unroll
        for (int m = 0; m < 16; ++m) {
            f4v wa = w4[m * 128 + lane];
            f4v wb = w4[m * 128 + 64 + lane];   // pad entries are zero
            acc[m]      += dot4(a0, wa) + dot4(b0, wb);
            acc[16 + m] += dot4(a1, wa) + dot4(b1, wb);
        }

        // bisection reduce: 32 values over 64 lanes
        #pragma unroll
        for (int i = 0; i < 16; ++i) {
            float keep = (lane & 1) ? acc[i + 16] : acc[i];
            float send = (lane & 1) ? acc[i]      : acc[i + 16];
            acc[i] = keep + __shfl_xor(send, 1);
        }
        #pragma unroll
        for (int i = 0; i < 8; ++i) {
            float keep = (lane & 2) ? acc[i + 8] : acc[i];
            float send = (lane & 2) ? acc[i]     : acc[i + 8];
            acc[i] = keep + __shfl_xor(send, 2);
        }
        #pragma unroll
        for (int i = 0; i < 4; ++i) {
            float keep = (lane & 4) ? acc[i + 4] : acc[i];
            float send = (lane & 4) ? acc[i]     : acc[i + 4];
            acc[i] = keep + __shfl_xor(send, 4);
        }
        #pragma unroll
        for (int i = 0; i < 2; ++i) {
            float keep = (lane & 8) ? acc[i + 2] : acc[i];
            float send = (lane & 8) ? acc[i]     : acc[i + 2];
            acc[i] = keep + __shfl_xor(send, 8);
        }
        {
            float keep = (lane & 16) ? acc[1] : acc[0];
            float send = (lane & 16) ? acc[0] : acc[1];
            acc[0] = keep + __shfl_xor(send, 16);
        }
        float tot = acc[0] + __shfl_xor(acc[0], 32);

        if (lane < 32) {
            int idx = ((lane & 1) << 4) | ((lane & 2) << 2) | (lane & 4)
                    | ((lane & 8) >> 2) | ((lane & 16) >> 4);
            int node = n0 + (idx >> 4);
            int m = idx & 15;
            if (node < N) {
                if (m < 8) yab[(size_t)node * 8 + m] = (unsigned short)f2bf(tot);
                else       yr[(size_t)node * 8 + m - 8] = tot;
            }
        }
    }
}

// Per-block LDS histogram over dst buckets (bucket = dst>>BSH).
__global__ __launch_bounds__(512) void hist_kernel(
    const int* __restrict__ ei, int E, int chunk, int B,
    int* __restrict__ hist_g)            // [B][P_BLOCKS]
{
    __shared__ int h[NBKT_MAX];
    for (int i = threadIdx.x; i < B; i += 512) h[i] = 0;
    __syncthreads();
    const int p = blockIdx.x;
    const int e0 = p * chunk, e1 = min(e0 + chunk, E);
    int e = e0 + threadIdx.x;
    for (; e + 512 < e1; e += 1024) {
        int d0 = ei[E + e], d1 = ei[E + e + 512];
        atomicAdd(&h[d0 >> BSH], 1);
        atomicAdd(&h[d1 >> BSH], 1);
    }
    for (; e < e1; e += 512) atomicAdd(&h[ei[E + e] >> BSH], 1);
    __syncthreads();
    for (int b = threadIdx.x; b < B; b += 512)
        hist_g[(size_t)b * P_BLOCKS + p] = h[b];
}

// tot[b] = sum_p hist[b][p]
__global__ __launch_bounds__(256) void bsum_kernel(
    const int* __restrict__ hist_g, int* __restrict__ tot)
{
    __shared__ int s[256];
    const int b = blockIdx.x;
    s[threadIdx.x] = hist_g[(size_t)b * P_BLOCKS + threadIdx.x];
    __syncthreads();
    for (int o = 128; o > 0; o >>= 1) {
        if (threadIdx.x < o) s[threadIdx.x] += s[threadIdx.x + o];
        __syncthreads();
    }
    if (threadIdx.x == 0) tot[b] = s[0];
}

// In-place: hist_g[b][p] <- bstart[b] + exclusive_scan_p(hist[b][p]).
__global__ __launch_bounds__(256) void base_kernel(
    int* __restrict__ hist_g, const int* __restrict__ tot, int B,
    int* __restrict__ bstart)
{
    __shared__ int sr[256];
    __shared__ int s2[256];
    __shared__ int bs_sh;
    const int b = blockIdx.x, tid = threadIdx.x;

    int part = 0;
    for (int i = tid; i < b; i += 256) part += tot[i];
    sr[tid] = part;
    __syncthreads();
    for (int o = 128; o > 0; o >>= 1) {
        if (tid < o) sr[tid] += sr[tid + o];
        __syncthreads();
    }
    if (tid == 0) bs_sh = sr[0];
    __syncthreads();
    const int bs = bs_sh;

    const int v = hist_g[(size_t)b * P_BLOCKS + tid];
    s2[tid] = v;
    __syncthreads();
    for (int o = 1; o < 256; o <<= 1) {
        int t = (tid >= o) ? s2[tid - o] : 0;
        __syncthreads();
        s2[tid] += t;
        __syncthreads();
    }
    hist_g[(size_t)b * P_BLOCKS + tid] = bs + s2[tid] - v;   // exclusive base
    if (tid == 0) bstart[b] = bs;
    if (b == B - 1 && tid == 255) bstart[B] = bs + s2[255];
}

// Scatter packed (src | dstLow<<17) into bucket-partitioned csr using LDS cursors.
__global__ __launch_bounds__(512) void scatter2_kernel(
    const int* __restrict__ ei, int E, int chunk, int B,
    const int* __restrict__ base, unsigned* __restrict__ csr)
{
    __shared__ int cur[NBKT_MAX];
    const int p = blockIdx.x;
    for (int b = threadIdx.x; b < B; b += 512) cur[b] = base[(size_t)b * P_BLOCKS + p];
    __syncthreads();
    const int e0 = p * chunk, e1 = min(e0 + chunk, E);
    int e = e0 + threadIdx.x;
    for (; e + 512 < e1; e += 1024) {
        int s0 = ei[e],     s1 = ei[e + 512];
        int d0 = ei[E + e], d1 = ei[E + e + 512];
        int p0 = atomicAdd(&cur[d0 >> BSH], 1);
        int p1 = atomicAdd(&cur[d1 >> BSH], 1);
        csr[p0] = (unsigned)s0 | ((unsigned)(d0 & (BSZ - 1)) << 17);
        csr[p1] = (unsigned)s1 | ((unsigned)(d1 & (BSZ - 1)) << 17);
    }
    for (; e < e1; e += 512) {
        int s0 = ei[e], d0 = ei[E + e];
        int p0 = atomicAdd(&cur[d0 >> BSH], 1);
        csr[p0] = (unsigned)s0 | ((unsigned)(d0 & (BSZ - 1)) << 17);
    }
}

// Layer-1 aggregation: 1 lane per edge reads the full 16B bf16 ya row
// (table 1.6 MB -> L2-resident). LDS f32 accumulate; fused epilogue.
__global__ __launch_bounds__(256) void agg1B_kernel(
    const int* __restrict__ bstart,
    const unsigned* __restrict__ csr,
    const unsigned short* __restrict__ yab, // [N,8] bf16
    const float* __restrict__ yr,    // [N,8] f32
    const float* __restrict__ b1,    // [8]
    const float* __restrict__ W2l,   // [10,8]
    const float* __restrict__ b2,    // [10]
    const float* __restrict__ W2r,   // [10,8]
    unsigned short* __restrict__ zlb, // [N,16] bf16 rows (32B): [v0..v4 _ _ _ | v5..v9 _ _ _]
    float* __restrict__ zrb,         // [N,12]  (col10 = invdeg)
    int N)
{
    __shared__ float acc[BSZ * 9];
    __shared__ int   cnt[BSZ];
    __shared__ float wb[178];        // b1[8] | W2l[80] | b2[10] | W2r[80]
    const int tid = threadIdx.x;
    for (int i = tid; i < BSZ * 9; i += 256) acc[i] = 0.f;
    if (tid < BSZ) cnt[tid] = 0;
    if (tid < 178)
        wb[tid] = (tid < 8) ? b1[tid] : (tid < 88) ? W2l[tid - 8]
                 : (tid < 98) ? b2[tid - 88] : W2r[tid - 98];
    __syncthreads();

    const int b = blockIdx.x;
    const int e0 = bstart[b], e1 = bstart[b + 1];
    const uint4* ya4 = reinterpret_cast<const uint4*>(yab);

    int e = e0 + tid;
    for (; e < e1; e += 256) {
        unsigned pk = csr[e];
        unsigned s = pk & 0x1FFFFu;
        int dl = pk >> 17;
        uint4 r = ya4[s];                 // 8 bf16
        float* A = acc + dl * 9;
        atomicAdd(A + 0, bflo(r.x)); atomicAdd(A + 1, bfhi(r.x));
        atomicAdd(A + 2, bflo(r.y)); atomicAdd(A + 3, bfhi(r.y));
        atomicAdd(A + 4, bflo(r.z)); atomicAdd(A + 5, bfhi(r.z));
        atomicAdd(A + 6, bflo(r.w)); atomicAdd(A + 7, bfhi(r.w));
        atomicAdd(&cnt[dl], 1);
    }
    __syncthreads();

    if (tid >= BSZ) return;
    const int node = b * BSZ + tid;
    if (node >= N) return;
    const float inv = 1.f / fmaxf((float)cnt[tid], 1.f);
    const float* rrp = yr + (size_t)node * 8;
    const float* A = acc + tid * 9;

    float h[8];
    #pragma unroll
    for (int t = 0; t < 8; ++t) {
        float v = A[t] * inv + wb[t] + rrp[t];
        h[t] = v > 0.f ? v : expm1f(v);   // ELU(alpha=1)
    }

    float zlv[10], zrv[10];
    #pragma unroll
    for (int k = 0; k < 10; ++k) {
        float al = 0.f, ar = wb[88 + k];
        #pragma unroll
        for (int t = 0; t < 8; ++t) {
            al += wb[8 + k * 8 + t]  * h[t];
            ar += wb[98 + k * 8 + t] * h[t];
        }
        zlv[k] = al; zrv[k] = ar;
    }

    // pack zl row: half0 = v0..v4, half1 = v5..v9 (bf16, 16B each)
    uint4 h0, h1;
    h0.x = f2bf(zlv[0]) | (f2bf(zlv[1]) << 16);
    h0.y = f2bf(zlv[2]) | (f2bf(zlv[3]) << 16);
    h0.z = f2bf(zlv[4]);
    h0.w = 0u;
    h1.x = f2bf(zlv[5]) | (f2bf(zlv[6]) << 16);
    h1.y = f2bf(zlv[7]) | (f2bf(zlv[8]) << 16);
    h1.z = f2bf(zlv[9]);
    h1.w = 0u;
    uint4* zl4w = reinterpret_cast<uint4*>(zlb + (size_t)node * 16);
    zl4w[0] = h0;
    zl4w[1] = h1;

    float4* zr4w = reinterpret_cast<float4*>(zrb + (size_t)node * 12);
    zr4w[0] = make_float4(zrv[0], zrv[1], zrv[2], zrv[3]);
    zr4w[1] = make_float4(zrv[4], zrv[5], zrv[6], zrv[7]);
    zr4w[2] = make_float4(zrv[8], zrv[9], inv, 0.f);   // col10 = invdeg
}

// Layer-2 aggregation: 2 lanes per edge, each reads one 16B half of the
// bf16 zl row (table 3.2 MB -> L2-resident) and does 5 LDS f32 atomics.
// Fused mean + r-branch + log-softmax.
__global__ __launch_bounds__(256) void agg2B_kernel(
    const int* __restrict__ bstart,
    const unsigned* __restrict__ csr,
    const unsigned short* __restrict__ zlb, // [N,16] bf16
    const float* __restrict__ zrb,   // [N,12] (col10 = invdeg)
    float* __restrict__ out,         // [N,10]
    int N)
{
    __shared__ float acc[BSZ * 17];
    const int tid = threadIdx.x;
    for (int i = tid; i < BSZ * 17; i += 256) acc[i] = 0.f;
    __syncthreads();

    const int b = blockIdx.x;
    const int e0 = bstart[b], e1 = bstart[b + 1];
    const uint4* zl4 = reinterpret_cast<const uint4*>(zlb);
    const int q = tid & 1;                  // half selector
    int e = e0 + (tid >> 1);
    for (; e + 128 < e1; e += 256) {
        unsigned pk0 = csr[e], pk1 = csr[e + 128];
        uint4 r0 = zl4[(size_t)(pk0 & 0x1FFFFu) * 2 + q];
        uint4 r1 = zl4[(size_t)(pk1 & 0x1FFFFu) * 2 + q];
        int dl0 = pk0 >> 17, dl1 = pk1 >> 17;
        float* A0 = acc + dl0 * 17 + q * 5;
        float* A1 = acc + dl1 * 17 + q * 5;
        atomicAdd(A0 + 0, bflo(r0.x)); atomicAdd(A0 + 1, bfhi(r0.x));
        atomicAdd(A0 + 2, bflo(r0.y)); atomicAdd(A0 + 3, bfhi(r0.y));
        atomicAdd(A0 + 4, bflo(r0.z));
        atomicAdd(A1 + 0, bflo(r1.x)); atomicAdd(A1 + 1, bfhi(r1.x));
        atomicAdd(A1 + 2, bflo(r1.y)); atomicAdd(A1 + 3, bfhi(r1.y));
        atomicAdd(A1 + 4, bflo(r1.z));
    }
    for (; e < e1; e += 128) {
        unsigned pk0 = csr[e];
        uint4 r0 = zl4[(size_t)(pk0 & 0x1FFFFu) * 2 + q];
        int dl0 = pk0 >> 17;
        float* A0 = acc + dl0 * 17 + q * 5;
        atomicAdd(A0 + 0, bflo(r0.x)); atomicAdd(A0 + 1, bfhi(r0.x));
        atomicAdd(A0 + 2, bflo(r0.y)); atomicAdd(A0 + 3, bfhi(r0.y));
        atomicAdd(A0 + 4, bflo(r0.z));
    }
    __syncthreads();

    if (tid >= BSZ) return;
    const int node = b * BSZ + tid;
    if (node >= N) return;
    const float* zr = zrb + (size_t)node * 12;
    const float inv = zr[10];
    const float* A = acc + tid * 17;
    float v[10];
    float mx = -1e30f;
    #pragma unroll
    for (int k = 0; k < 10; ++k) {
        v[k] = A[k] * inv + zr[k];
        mx = fmaxf(mx, v[k]);
    }
    float ssum = 0.f;
    #pragma unroll
    for (int k = 0; k < 10; ++k) ssum += expf(v[k] - mx);
    const float lse = mx + logf(ssum);
    float2* o = reinterpret_cast<float2*>(out + (size_t)node * 10);
    o[0] = make_float2(v[0] - lse, v[1] - lse);
    o[1] = make_float2(v[2] - lse, v[3] - lse);
    o[2] = make_float2(v[4] - lse, v[5] - lse);
    o[3] = make_float2(v[6] - lse, v[7] - lse);
    o[4] = make_float2(v[8] - lse, v[9] - lse);
}

extern "C" void kernel_launch(void* const* d_in, const int* in_sizes, int n_in,
                              void* d_out, int out_size, void* d_ws, size_t ws_size,
                              hipStream_t stream) {
    const float* x   = (const float*)d_in[0];
    const int*   ei  = (const int*)d_in[1];
    const float* W1l = (const float*)d_in[2];
    const float* b1l = (const float*)d_in[3];
    const float* W1r = (const float*)d_in[4];
    const float* W2l = (const float*)d_in[5];
    const float* b2l = (const float*)d_in[6];
    const float* W2r = (const float*)d_in[7];
    float* out = (float*)d_out;

    const int N = in_sizes[0] / 500;
    const int E = in_sizes[1] / 2;
    const int B = (N + BSZ - 1) >> BSH;       // buckets of BSZ nodes
    const int chunk = (E + P_BLOCKS - 1) / P_BLOCKS;

    // workspace: ints first, then 16B-aligned arrays
    int* hist_g  = (int*)d_ws;                       // [B*P_BLOCKS] (hist, then base in-place)
    int* tot     = hist_g + (size_t)B * P_BLOCKS;    // [B]
    int* bstart  = tot + B;                          // [B+1]
    unsigned* csr = (unsigned*)(bstart + B + 1);     // [E]
    size_t off = ((char*)(csr + E) - (char*)d_ws + 15) & ~(size_t)15;
    unsigned short* yab = (unsigned short*)((char*)d_ws + off);  // [N,8] bf16
    off = (off + (size_t)N * 16 + 15) & ~(size_t)15;
    unsigned short* zlb = (unsigned short*)((char*)d_ws + off);  // [N,16] bf16
    off = (off + (size_t)N * 32 + 15) & ~(size_t)15;
    float* yr  = (float*)((char*)d_ws + off);                    // [N,8] f32
    float* zrb = yr + (size_t)8 * N;                             // [N,12] f32

    proj1_kernel<<<1280, 256, 0, stream>>>(x, W1l, W1r, yab, yr, N);
    hist_kernel<<<P_BLOCKS, 512, 0, stream>>>(ei, E, chunk, B, hist_g);
    bsum_kernel<<<B, 256, 0, stream>>>(hist_g, tot);
    base_kernel<<<B, 256, 0, stream>>>(hist_g, tot, B, bstart);
    scatter2_kernel<<<P_BLOCKS, 512, 0, stream>>>(ei, E, chunk, B, hist_g, csr);
    agg1B_kernel<<<B, 256, 0, stream>>>(bstart, csr, yab, yr, b1l, W2l, b2l, W2r,
                                        zlb, zrb, N);
    agg2B_kernel<<<B, 256, 0, stream>>>(bstart, csr, zlb, zrb, out, N);
}

// Round 9
// 221.848 us; speedup vs baseline: 14.3390x; 2.1934x over previous
//
#include <hip/hip_runtime.h>
#include <hip/hip_bf16.h>
#include <math.h>

// GraphSAGE 2-layer, mean aggregation, N=100000, F=500, hid=8, classes=10.
// Project-before-aggregate + bucketed counting-sort CSR (no global atomics).
// Round 9: full per-dst sort within buckets (sortB) + register-accumulating
// aggregation (4 lanes/node, shfl-combine) — ZERO LDS atomics in agg kernels.
// R4-R8 showed agg time invariant to memory traffic (216/191/189/188 us at
// 65/185/129/22 MB fetch): the ~10 LDS f32 atomics/edge were the bottleneck.

#define NBKT_MAX 1600     // max buckets (N <= 102400)
#define P_BLOCKS 256      // partition blocks for hist/scatter
#define BSH 6             // bucket shift: 64 nodes/bucket
#define BSZ 64
#define SEG_CAP 4096      // max edges per bucket segment (mean 2048, sigma 45)

typedef float f4v __attribute__((ext_vector_type(4)));

__device__ __forceinline__ float dot4(f4v a, f4v b) {
    return a.x * b.x + a.y * b.y + a.z * b.z + a.w * b.w;
}
__device__ __forceinline__ unsigned f2bf(float f) {   // RNE f32->bf16 bits
    unsigned u = __float_as_uint(f);
    return (u + 0x7FFFu + ((u >> 16) & 1u)) >> 16;
}
__device__ __forceinline__ float bflo(unsigned w) { return __uint_as_float(w << 16); }
__device__ __forceinline__ float bfhi(unsigned w) { return __uint_as_float(w & 0xFFFF0000u); }

// Coalesced projection: each wave handles 2 nodes per iteration.
// ya written as bf16 (16B rows), yr kept f32 (read once, per-node).
__global__ __launch_bounds__(256) void proj1_kernel(
    const float* __restrict__ x,
    const float* __restrict__ W1l,   // [8,500]
    const float* __restrict__ W1r,   // [8,500]
    unsigned short* __restrict__ yab, // [N,8] bf16 = x@W1l.T (aggregated part)
    float* __restrict__ yr,           // [N,8] f32  = x@W1r.T (self part)
    int N)
{
    __shared__ __align__(16) float wlds[16 * 512];   // rows padded 500->512
    for (int idx = threadIdx.x; idx < 16 * 512; idx += 256) {
        int k = idx >> 9, j = idx & 511;
        float v = 0.f;
        if (j < 500) v = (k < 8) ? W1l[k * 500 + j] : W1r[(k - 8) * 500 + j];
        wlds[idx] = v;
    }
    __syncthreads();

    const int lane = threadIdx.x & 63;
    const int wv   = threadIdx.x >> 6;
    const f4v* w4 = reinterpret_cast<const f4v*>(wlds);

    const int P = (N + 1) >> 1;                 // node pairs
    const int gw = blockIdx.x * 4 + wv;
    const int nw = gridDim.x * 4;
    const f4v zero = {0.f, 0.f, 0.f, 0.f};

    for (int p = gw; p < P; p += nw) {
        const int n0 = p * 2;
        const int n1 = min(n0 + 1, N - 1);
        const f4v* xr0 = reinterpret_cast<const f4v*>(x + (size_t)n0 * 500);
        const f4v* xr1 = reinterpret_cast<const f4v*>(x + (size_t)n1 * 500);
        f4v a0 = xr0[lane];
        f4v a1 = xr1[lane];
        f4v b0 = (lane < 61) ? xr0[64 + lane] : zero;
        f4v b1 = (lane < 61) ? xr1[64 + lane] : zero;

        float acc[32];
        #pragma unroll
        for (int i = 0; i < 32; ++i) acc[i] = 0.f;

        #pragma unroll
        for (int m = 0; m < 16; ++m) {
            f4v wa = w4[m * 128 + lane];
            f4v wb = w4[m * 128 + 64 + lane];   // pad entries are zero
            acc[m]      += dot4(a0, wa) + dot4(b0, wb);
            acc[16 + m] += dot4(a1, wa) + dot4(b1, wb);
        }

        // bisection reduce: 32 values over 64 lanes
        #pragma unroll
        for (int i = 0; i < 16; ++i) {
            float keep = (lane & 1) ? acc[i + 16] : acc[i];
            float send = (lane & 1) ? acc[i]      : acc[i + 16];
            acc[i] = keep + __shfl_xor(send, 1);
        }
        #pragma unroll
        for (int i = 0; i < 8; ++i) {
            float keep = (lane & 2) ? acc[i + 8] : acc[i];
            float send = (lane & 2) ? acc[i]     : acc[i + 8];
            acc[i] = keep + __shfl_xor(send, 2);
        }
        #pragma unroll
        for (int i = 0; i < 4; ++i) {
            float keep = (lane & 4) ? acc[i + 4] : acc[i];
            float send = (lane & 4) ? acc[i]     : acc[i + 4];
            acc[i] = keep + __shfl_xor(send, 4);
        }
        #pragma unroll
        for (int i = 0; i < 2; ++i) {
            float keep = (lane & 8) ? acc[i + 2] : acc[i];
            float send = (lane & 8) ? acc[i]     : acc[i + 2];
            acc[i] = keep + __shfl_xor(send, 8);
        }
        {
            float keep = (lane & 16) ? acc[1] : acc[0];
            float send = (lane & 16) ? acc[0] : acc[1];
            acc[0] = keep + __shfl_xor(send, 16);
        }
        float tot = acc[0] + __shfl_xor(acc[0], 32);

        if (lane < 32) {
            int idx = ((lane & 1) << 4) | ((lane & 2) << 2) | (lane & 4)
                    | ((lane & 8) >> 2) | ((lane & 16) >> 4);
            int node = n0 + (idx >> 4);
            int m = idx & 15;
            if (node < N) {
                if (m < 8) yab[(size_t)node * 8 + m] = (unsigned short)f2bf(tot);
                else       yr[(size_t)node * 8 + m - 8] = tot;
            }
        }
    }
}

// Per-block LDS histogram over dst buckets (bucket = dst>>BSH).
__global__ __launch_bounds__(512) void hist_kernel(
    const int* __restrict__ ei, int E, int chunk, int B,
    int* __restrict__ hist_g)            // [B][P_BLOCKS]
{
    __shared__ int h[NBKT_MAX];
    for (int i = threadIdx.x; i < B; i += 512) h[i] = 0;
    __syncthreads();
    const int p = blockIdx.x;
    const int e0 = p * chunk, e1 = min(e0 + chunk, E);
    int e = e0 + threadIdx.x;
    for (; e + 512 < e1; e += 1024) {
        int d0 = ei[E + e], d1 = ei[E + e + 512];
        atomicAdd(&h[d0 >> BSH], 1);
        atomicAdd(&h[d1 >> BSH], 1);
    }
    for (; e < e1; e += 512) atomicAdd(&h[ei[E + e] >> BSH], 1);
    __syncthreads();
    for (int b = threadIdx.x; b < B; b += 512)
        hist_g[(size_t)b * P_BLOCKS + p] = h[b];
}

// tot[b] = sum_p hist[b][p]
__global__ __launch_bounds__(256) void bsum_kernel(
    const int* __restrict__ hist_g, int* __restrict__ tot)
{
    __shared__ int s[256];
    const int b = blockIdx.x;
    s[threadIdx.x] = hist_g[(size_t)b * P_BLOCKS + threadIdx.x];
    __syncthreads();
    for (int o = 128; o > 0; o >>= 1) {
        if (threadIdx.x < o) s[threadIdx.x] += s[threadIdx.x + o];
        __syncthreads();
    }
    if (threadIdx.x == 0) tot[b] = s[0];
}

// In-place: hist_g[b][p] <- bstart[b] + exclusive_scan_p(hist[b][p]).
__global__ __launch_bounds__(256) void base_kernel(
    int* __restrict__ hist_g, const int* __restrict__ tot, int B,
    int* __restrict__ bstart)
{
    __shared__ int sr[256];
    __shared__ int s2[256];
    __shared__ int bs_sh;
    const int b = blockIdx.x, tid = threadIdx.x;

    int part = 0;
    for (int i = tid; i < b; i += 256) part += tot[i];
    sr[tid] = part;
    __syncthreads();
    for (int o = 128; o > 0; o >>= 1) {
        if (tid < o) sr[tid] += sr[tid + o];
        __syncthreads();
    }
    if (tid == 0) bs_sh = sr[0];
    __syncthreads();
    const int bs = bs_sh;

    const int v = hist_g[(size_t)b * P_BLOCKS + tid];
    s2[tid] = v;
    __syncthreads();
    for (int o = 1; o < 256; o <<= 1) {
        int t = (tid >= o) ? s2[tid - o] : 0;
        __syncthreads();
        s2[tid] += t;
        __syncthreads();
    }
    hist_g[(size_t)b * P_BLOCKS + tid] = bs + s2[tid] - v;   // exclusive base
    if (tid == 0) bstart[b] = bs;
    if (b == B - 1 && tid == 255) bstart[B] = bs + s2[255];
}

// Scatter packed (src | dstLow<<17) into bucket-partitioned csr using LDS cursors.
__global__ __launch_bounds__(512) void scatter2_kernel(
    const int* __restrict__ ei, int E, int chunk, int B,
    const int* __restrict__ base, unsigned* __restrict__ csr)
{
    __shared__ int cur[NBKT_MAX];
    const int p = blockIdx.x;
    for (int b = threadIdx.x; b < B; b += 512) cur[b] = base[(size_t)b * P_BLOCKS + p];
    __syncthreads();
    const int e0 = p * chunk, e1 = min(e0 + chunk, E);
    int e = e0 + threadIdx.x;
    for (; e + 512 < e1; e += 1024) {
        int s0 = ei[e],     s1 = ei[e + 512];
        int d0 = ei[E + e], d1 = ei[E + e + 512];
        int p0 = atomicAdd(&cur[d0 >> BSH], 1);
        int p1 = atomicAdd(&cur[d1 >> BSH], 1);
        csr[p0] = (unsigned)s0 | ((unsigned)(d0 & (BSZ - 1)) << 17);
        csr[p1] = (unsigned)s1 | ((unsigned)(d1 & (BSZ - 1)) << 17);
    }
    for (; e < e1; e += 512) {
        int s0 = ei[e], d0 = ei[E + e];
        int p0 = atomicAdd(&cur[d0 >> BSH], 1);
        csr[p0] = (unsigned)s0 | ((unsigned)(d0 & (BSZ - 1)) << 17);
    }
}

// Per-bucket counting sort by dst node (in-place via LDS staging).
// Segment <= SEG_CAP (mean 2048, 45-sigma margin). Writes nodeoff[] and
// rewrites csr[] sorted, storing only the src index.
__global__ __launch_bounds__(256) void sortB_kernel(
    const int* __restrict__ bstart,
    unsigned* __restrict__ csr,
    int* __restrict__ nodeoff,       // [B*64+1]
    int B)
{
    __shared__ unsigned stage[SEG_CAP];
    __shared__ int cnt[BSZ];
    __shared__ int cur[BSZ];
    const int b = blockIdx.x, tid = threadIdx.x;
    const int e0 = bstart[b], e1 = bstart[b + 1];
    const int n = e1 - e0;

    if (tid < BSZ) cnt[tid] = 0;
    for (int i = tid; i < n; i += 256) stage[i] = csr[e0 + i];
    __syncthreads();
    for (int i = tid; i < n; i += 256) atomicAdd(&cnt[stage[i] >> 17], 1);
    __syncthreads();
    if (tid < BSZ) {
        int v = cnt[tid];
        int incl = v;
        #pragma unroll
        for (int o = 1; o < 64; o <<= 1) {
            int t = __shfl_up(incl, o);
            if ((tid & 63) >= o) incl += t;
        }
        int excl = e0 + incl - v;
        cur[tid] = excl;
        nodeoff[(size_t)b * BSZ + tid] = excl;
        if (b == B - 1 && tid == 0) nodeoff[(size_t)B * BSZ] = e1;
    }
    __syncthreads();
    for (int i = tid; i < n; i += 256) {
        unsigned pk = stage[i];
        int pos = atomicAdd(&cur[pk >> 17], 1);
        csr[pos] = pk & 0x1FFFFu;
    }
}

// Layer-1 aggregation, atomic-free: 4 lanes per node stride its contiguous
// edge list, accumulate 8 f32 in registers, shfl-combine, lane-0 epilogue
// (mean + bias + self + ELU + both layer-2 projections).
__global__ __launch_bounds__(256) void agg1R_kernel(
    const int* __restrict__ nodeoff,
    const unsigned* __restrict__ csr,     // sorted src indices
    const unsigned short* __restrict__ yab, // [N,8] bf16
    const float* __restrict__ yr,    // [N,8] f32
    const float* __restrict__ b1,    // [8]
    const float* __restrict__ W2l,   // [10,8]
    const float* __restrict__ b2,    // [10]
    const float* __restrict__ W2r,   // [10,8]
    unsigned short* __restrict__ zlb, // [N,16] bf16 rows (32B)
    float* __restrict__ zrb,         // [N,12]  (col10 = invdeg)
    int N)
{
    __shared__ float wb[178];        // b1[8] | W2l[80] | b2[10] | W2r[80]
    const int tid = threadIdx.x;
    if (tid < 178)
        wb[tid] = (tid < 8) ? b1[tid] : (tid < 88) ? W2l[tid - 8]
                 : (tid < 98) ? b2[tid - 88] : W2r[tid - 98];
    __syncthreads();

    const int g = tid >> 2;          // node slot 0..63
    const int q = tid & 3;
    const int node = blockIdx.x * BSZ + g;
    const int gs = nodeoff[node], ge = nodeoff[node + 1];
    const uint4* ya4 = reinterpret_cast<const uint4*>(yab);

    float a[8];
    #pragma unroll
    for (int i = 0; i < 8; ++i) a[i] = 0.f;

    for (int e = gs + q; e < ge; e += 4) {
        unsigned s = csr[e];
        uint4 r = ya4[s];
        a[0] += bflo(r.x); a[1] += bfhi(r.x);
        a[2] += bflo(r.y); a[3] += bfhi(r.y);
        a[4] += bflo(r.z); a[5] += bfhi(r.z);
        a[6] += bflo(r.w); a[7] += bfhi(r.w);
    }
    #pragma unroll
    for (int i = 0; i < 8; ++i) {
        a[i] += __shfl_xor(a[i], 1);
        a[i] += __shfl_xor(a[i], 2);
    }

    if (q != 0 || node >= N) return;
    const int deg = ge - gs;
    const float inv = 1.f / fmaxf((float)deg, 1.f);
    const f4v* yr4 = reinterpret_cast<const f4v*>(yr + (size_t)node * 8);
    f4v r0 = yr4[0], r1 = yr4[1];
    const float rr[8] = {r0.x, r0.y, r0.z, r0.w, r1.x, r1.y, r1.z, r1.w};

    float h[8];
    #pragma unroll
    for (int t = 0; t < 8; ++t) {
        float v = a[t] * inv + wb[t] + rr[t];
        h[t] = v > 0.f ? v : expm1f(v);   // ELU(alpha=1)
    }

    float zlv[10], zrv[10];
    #pragma unroll
    for (int k = 0; k < 10; ++k) {
        float al = 0.f, ar = wb[88 + k];
        #pragma unroll
        for (int t = 0; t < 8; ++t) {
            al += wb[8 + k * 8 + t]  * h[t];
            ar += wb[98 + k * 8 + t] * h[t];
        }
        zlv[k] = al; zrv[k] = ar;
    }

    uint4 h0, h1;
    h0.x = f2bf(zlv[0]) | (f2bf(zlv[1]) << 16);
    h0.y = f2bf(zlv[2]) | (f2bf(zlv[3]) << 16);
    h0.z = f2bf(zlv[4]);
    h0.w = 0u;
    h1.x = f2bf(zlv[5]) | (f2bf(zlv[6]) << 16);
    h1.y = f2bf(zlv[7]) | (f2bf(zlv[8]) << 16);
    h1.z = f2bf(zlv[9]);
    h1.w = 0u;
    uint4* zl4w = reinterpret_cast<uint4*>(zlb + (size_t)node * 16);
    zl4w[0] = h0;
    zl4w[1] = h1;

    float4* zr4w = reinterpret_cast<float4*>(zrb + (size_t)node * 12);
    zr4w[0] = make_float4(zrv[0], zrv[1], zrv[2], zrv[3]);
    zr4w[1] = make_float4(zrv[4], zrv[5], zrv[6], zrv[7]);
    zr4w[2] = make_float4(zrv[8], zrv[9], inv, 0.f);   // col10 = invdeg
}

// Layer-2 aggregation, atomic-free: 4 lanes per node, register accumulate
// 10 f32, shfl-combine, lane-0 does mean + r-branch + log-softmax.
__global__ __launch_bounds__(256) void agg2R_kernel(
    const int* __restrict__ nodeoff,
    const unsigned* __restrict__ csr,     // sorted src indices
    const unsigned short* __restrict__ zlb, // [N,16] bf16
    const float* __restrict__ zrb,   // [N,12] (col10 = invdeg)
    float* __restrict__ out,         // [N,10]
    int N)
{
    const int tid = threadIdx.x;
    const int g = tid >> 2;
    const int q = tid & 3;
    const int node = blockIdx.x * BSZ + g;
    const int gs = nodeoff[node], ge = nodeoff[node + 1];
    const uint4* zl4 = reinterpret_cast<const uint4*>(zlb);

    float a[10];
    #pragma unroll
    for (int i = 0; i < 10; ++i) a[i] = 0.f;

    for (int e = gs + q; e < ge; e += 4) {
        unsigned s = csr[e];
        uint4 rA = zl4[(size_t)s * 2];
        uint4 rB = zl4[(size_t)s * 2 + 1];
        a[0] += bflo(rA.x); a[1] += bfhi(rA.x);
        a[2] += bflo(rA.y); a[3] += bfhi(rA.y);
        a[4] += bflo(rA.z);
        a[5] += bflo(rB.x); a[6] += bfhi(rB.x);
        a[7] += bflo(rB.y); a[8] += bfhi(rB.y);
        a[9] += bflo(rB.z);
    }
    #pragma unroll
    for (int i = 0; i < 10; ++i) {
        a[i] += __shfl_xor(a[i], 1);
        a[i] += __shfl_xor(a[i], 2);
    }

    if (q != 0 || node >= N) return;
    const float* zr = zrb + (size_t)node * 12;
    const float inv = zr[10];
    float v[10];
    float mx = -1e30f;
    #pragma unroll
    for (int k = 0; k < 10; ++k) {
        v[k] = a[k] * inv + zr[k];
        mx = fmaxf(mx, v[k]);
    }
    float ssum = 0.f;
    #pragma unroll
    for (int k = 0; k < 10; ++k) ssum += expf(v[k] - mx);
    const float lse = mx + logf(ssum);
    float2* o = reinterpret_cast<float2*>(out + (size_t)node * 10);
    o[0] = make_float2(v[0] - lse, v[1] - lse);
    o[1] = make_float2(v[2] - lse, v[3] - lse);
    o[2] = make_float2(v[4] - lse, v[5] - lse);
    o[3] = make_float2(v[6] - lse, v[7] - lse);
    o[4] = make_float2(v[8] - lse, v[9] - lse);
}

extern "C" void kernel_launch(void* const* d_in, const int* in_sizes, int n_in,
                              void* d_out, int out_size, void* d_ws, size_t ws_size,
                              hipStream_t stream) {
    const float* x   = (const float*)d_in[0];
    const int*   ei  = (const int*)d_in[1];
    const float* W1l = (const float*)d_in[2];
    const float* b1l = (const float*)d_in[3];
    const float* W1r = (const float*)d_in[4];
    const float* W2l = (const float*)d_in[5];
    const float* b2l = (const float*)d_in[6];
    const float* W2r = (const float*)d_in[7];
    float* out = (float*)d_out;

    const int N = in_sizes[0] / 500;
    const int E = in_sizes[1] / 2;
    const int B = (N + BSZ - 1) >> BSH;       // buckets of BSZ nodes
    const int chunk = (E + P_BLOCKS - 1) / P_BLOCKS;

    // workspace: ints first, then 16B-aligned arrays (~33 MB)
    int* hist_g  = (int*)d_ws;                       // [B*P_BLOCKS] (hist, then base in-place)
    int* tot     = hist_g + (size_t)B * P_BLOCKS;    // [B]
    int* bstart  = tot + B;                          // [B+1]
    int* nodeoff = bstart + (B + 1);                 // [B*64+1]
    unsigned* csr = (unsigned*)(nodeoff + (size_t)B * BSZ + 1); // [E]
    size_t off = ((char*)(csr + E) - (char*)d_ws + 15) & ~(size_t)15;
    unsigned short* yab = (unsigned short*)((char*)d_ws + off);  // [N,8] bf16
    off = (off + (size_t)N * 16 + 15) & ~(size_t)15;
    unsigned short* zlb = (unsigned short*)((char*)d_ws + off);  // [N,16] bf16
    off = (off + (size_t)N * 32 + 15) & ~(size_t)15;
    float* yr  = (float*)((char*)d_ws + off);                    // [N,8] f32
    float* zrb = yr + (size_t)8 * N;                             // [N,12] f32

    proj1_kernel<<<1280, 256, 0, stream>>>(x, W1l, W1r, yab, yr, N);
    hist_kernel<<<P_BLOCKS, 512, 0, stream>>>(ei, E, chunk, B, hist_g);
    bsum_kernel<<<B, 256, 0, stream>>>(hist_g, tot);
    base_kernel<<<B, 256, 0, stream>>>(hist_g, tot, B, bstart);
    scatter2_kernel<<<P_BLOCKS, 512, 0, stream>>>(ei, E, chunk, B, hist_g, csr);
    sortB_kernel<<<B, 256, 0, stream>>>(bstart, csr, nodeoff, B);
    agg1R_kernel<<<B, 256, 0, stream>>>(nodeoff, csr, yab, yr, b1l, W2l, b2l, W2r,
                                        zlb, zrb, N);
    agg2R_kernel<<<B, 256, 0, stream>>>(nodeoff, csr, zlb, zrb, out, N);
}

// Round 10
// 190.795 us; speedup vs baseline: 16.6728x; 1.1628x over previous
//
#include <hip/hip_runtime.h>
#include <hip/hip_bf16.h>
#include <math.h>

// GraphSAGE 2-layer, mean aggregation, N=100000, F=500, hid=8, classes=10.
// Project-before-aggregate + bucketed counting-sort CSR (no global atomics)
// + per-dst sorted edge lists + register-accumulating aggregation (no LDS atomics).
// Round 10: proj1 software-pipelined (prefetch next pair's x rows into regs
// before computing current pair) + grid=1024 (exactly 4 blocks/CU).
// R9 evidence: proj1 ~2400cyc/pair vs ~840cyc work -> ~1500cyc unhidden HBM latency.

#define NBKT_MAX 1600     // max buckets (N <= 102400)
#define P_BLOCKS 256      // partition blocks for hist/scatter
#define BSH 6             // bucket shift: 64 nodes/bucket
#define BSZ 64
#define SEG_CAP 4096      // max edges per bucket segment (mean 2048, sigma 45)

typedef float f4v __attribute__((ext_vector_type(4)));

__device__ __forceinline__ float dot4(f4v a, f4v b) {
    return a.x * b.x + a.y * b.y + a.z * b.z + a.w * b.w;
}
__device__ __forceinline__ unsigned f2bf(float f) {   // RNE f32->bf16 bits
    unsigned u = __float_as_uint(f);
    return (u + 0x7FFFu + ((u >> 16) & 1u)) >> 16;
}
__device__ __forceinline__ float bflo(unsigned w) { return __uint_as_float(w << 16); }
__device__ __forceinline__ float bfhi(unsigned w) { return __uint_as_float(w & 0xFFFF0000u); }

// Coalesced projection, software-pipelined: each wave handles 2 nodes per
// iteration; next iteration's 4 x-row vectors are loaded before computing.
__global__ __launch_bounds__(256) void proj1_kernel(
    const float* __restrict__ x,
    const float* __restrict__ W1l,   // [8,500]
    const float* __restrict__ W1r,   // [8,500]
    unsigned short* __restrict__ yab, // [N,8] bf16 = x@W1l.T (aggregated part)
    float* __restrict__ yr,           // [N,8] f32  = x@W1r.T (self part)
    int N)
{
    __shared__ __align__(16) float wlds[16 * 512];   // rows padded 500->512
    for (int idx = threadIdx.x; idx < 16 * 512; idx += 256) {
        int k = idx >> 9, j = idx & 511;
        float v = 0.f;
        if (j < 500) v = (k < 8) ? W1l[k * 500 + j] : W1r[(k - 8) * 500 + j];
        wlds[idx] = v;
    }
    __syncthreads();

    const int lane = threadIdx.x & 63;
    const int wv   = threadIdx.x >> 6;
    const f4v* w4 = reinterpret_cast<const f4v*>(wlds);

    const int P = (N + 1) >> 1;                 // node pairs
    const int gw = blockIdx.x * 4 + wv;
    const int nw = gridDim.x * 4;
    const f4v zero = {0.f, 0.f, 0.f, 0.f};

    int p = gw;
    f4v a0 = zero, a1 = zero, b0 = zero, b1 = zero;
    if (p < P) {
        const int n0 = p * 2;
        const int n1 = min(n0 + 1, N - 1);
        const f4v* xr0 = reinterpret_cast<const f4v*>(x + (size_t)n0 * 500);
        const f4v* xr1 = reinterpret_cast<const f4v*>(x + (size_t)n1 * 500);
        a0 = xr0[lane];
        a1 = xr1[lane];
        b0 = (lane < 61) ? xr0[64 + lane] : zero;
        b1 = (lane < 61) ? xr1[64 + lane] : zero;
    }

    while (p < P) {
        const int pn = p + nw;
        f4v na0 = zero, na1 = zero, nb0 = zero, nb1 = zero;
        if (pn < P) {                       // issue next pair's loads NOW
            const int m0 = pn * 2;
            const int m1 = min(m0 + 1, N - 1);
            const f4v* q0 = reinterpret_cast<const f4v*>(x + (size_t)m0 * 500);
            const f4v* q1 = reinterpret_cast<const f4v*>(x + (size_t)m1 * 500);
            na0 = q0[lane];
            na1 = q1[lane];
            nb0 = (lane < 61) ? q0[64 + lane] : zero;
            nb1 = (lane < 61) ? q1[64 + lane] : zero;
        }

        float acc[32];
        #pragma unroll
        for (int i = 0; i < 32; ++i) acc[i] = 0.f;

        #pragma unroll
        for (int m = 0; m < 16; ++m) {
            f4v wa = w4[m * 128 + lane];
            f4v wb = w4[m * 128 + 64 + lane];   // pad entries are zero
            acc[m]      += dot4(a0, wa) + dot4(b0, wb);
            acc[16 + m] += dot4(a1, wa) + dot4(b1, wb);
        }

        // bisection reduce: 32 values over 64 lanes
        #pragma unroll
        for (int i = 0; i < 16; ++i) {
            float keep = (lane & 1) ? acc[i + 16] : acc[i];
            float send = (lane & 1) ? acc[i]      : acc[i + 16];
            acc[i] = keep + __shfl_xor(send, 1);
        }
        #pragma unroll
        for (int i = 0; i < 8; ++i) {
            float keep = (lane & 2) ? acc[i + 8] : acc[i];
            float send = (lane & 2) ? acc[i]     : acc[i + 8];
            acc[i] = keep + __shfl_xor(send, 2);
        }
        #pragma unroll
        for (int i = 0; i < 4; ++i) {
            float keep = (lane & 4) ? acc[i + 4] : acc[i];
            float send = (lane & 4) ? acc[i]     : acc[i + 4];
            acc[i] = keep + __shfl_xor(send, 4);
        }
        #pragma unroll
        for (int i = 0; i < 2; ++i) {
            float keep = (lane & 8) ? acc[i + 2] : acc[i];
            float send = (lane & 8) ? acc[i]     : acc[i + 2];
            acc[i] = keep + __shfl_xor(send, 8);
        }
        {
            float keep = (lane & 16) ? acc[1] : acc[0];
            float send = (lane & 16) ? acc[0] : acc[1];
            acc[0] = keep + __shfl_xor(send, 16);
        }
        float tot = acc[0] + __shfl_xor(acc[0], 32);

        if (lane < 32) {
            int idx = ((lane & 1) << 4) | ((lane & 2) << 2) | (lane & 4)
                    | ((lane & 8) >> 2) | ((lane & 16) >> 4);
            int node = p * 2 + (idx >> 4);
            int m = idx & 15;
            if (node < N) {
                if (m < 8) yab[(size_t)node * 8 + m] = (unsigned short)f2bf(tot);
                else       yr[(size_t)node * 8 + m - 8] = tot;
            }
        }

        a0 = na0; a1 = na1; b0 = nb0; b1 = nb1;
        p = pn;
    }
}

// Per-block LDS histogram over dst buckets (bucket = dst>>BSH).
__global__ __launch_bounds__(512) void hist_kernel(
    const int* __restrict__ ei, int E, int chunk, int B,
    int* __restrict__ hist_g)            // [B][P_BLOCKS]
{
    __shared__ int h[NBKT_MAX];
    for (int i = threadIdx.x; i < B; i += 512) h[i] = 0;
    __syncthreads();
    const int p = blockIdx.x;
    const int e0 = p * chunk, e1 = min(e0 + chunk, E);
    int e = e0 + threadIdx.x;
    for (; e + 512 < e1; e += 1024) {
        int d0 = ei[E + e], d1 = ei[E + e + 512];
        atomicAdd(&h[d0 >> BSH], 1);
        atomicAdd(&h[d1 >> BSH], 1);
    }
    for (; e < e1; e += 512) atomicAdd(&h[ei[E + e] >> BSH], 1);
    __syncthreads();
    for (int b = threadIdx.x; b < B; b += 512)
        hist_g[(size_t)b * P_BLOCKS + p] = h[b];
}

// tot[b] = sum_p hist[b][p]
__global__ __launch_bounds__(256) void bsum_kernel(
    const int* __restrict__ hist_g, int* __restrict__ tot)
{
    __shared__ int s[256];
    const int b = blockIdx.x;
    s[threadIdx.x] = hist_g[(size_t)b * P_BLOCKS + threadIdx.x];
    __syncthreads();
    for (int o = 128; o > 0; o >>= 1) {
        if (threadIdx.x < o) s[threadIdx.x] += s[threadIdx.x + o];
        __syncthreads();
    }
    if (threadIdx.x == 0) tot[b] = s[0];
}

// In-place: hist_g[b][p] <- bstart[b] + exclusive_scan_p(hist[b][p]).
__global__ __launch_bounds__(256) void base_kernel(
    int* __restrict__ hist_g, const int* __restrict__ tot, int B,
    int* __restrict__ bstart)
{
    __shared__ int sr[256];
    __shared__ int s2[256];
    __shared__ int bs_sh;
    const int b = blockIdx.x, tid = threadIdx.x;

    int part = 0;
    for (int i = tid; i < b; i += 256) part += tot[i];
    sr[tid] = part;
    __syncthreads();
    for (int o = 128; o > 0; o >>= 1) {
        if (tid < o) sr[tid] += sr[tid + o];
        __syncthreads();
    }
    if (tid == 0) bs_sh = sr[0];
    __syncthreads();
    const int bs = bs_sh;

    const int v = hist_g[(size_t)b * P_BLOCKS + tid];
    s2[tid] = v;
    __syncthreads();
    for (int o = 1; o < 256; o <<= 1) {
        int t = (tid >= o) ? s2[tid - o] : 0;
        __syncthreads();
        s2[tid] += t;
        __syncthreads();
    }
    hist_g[(size_t)b * P_BLOCKS + tid] = bs + s2[tid] - v;   // exclusive base
    if (tid == 0) bstart[b] = bs;
    if (b == B - 1 && tid == 255) bstart[B] = bs + s2[255];
}

// Scatter packed (src | dstLow<<17) into bucket-partitioned csr using LDS cursors.
__global__ __launch_bounds__(512) void scatter2_kernel(
    const int* __restrict__ ei, int E, int chunk, int B,
    const int* __restrict__ base, unsigned* __restrict__ csr)
{
    __shared__ int cur[NBKT_MAX];
    const int p = blockIdx.x;
    for (int b = threadIdx.x; b < B; b += 512) cur[b] = base[(size_t)b * P_BLOCKS + p];
    __syncthreads();
    const int e0 = p * chunk, e1 = min(e0 + chunk, E);
    int e = e0 + threadIdx.x;
    for (; e + 512 < e1; e += 1024) {
        int s0 = ei[e],     s1 = ei[e + 512];
        int d0 = ei[E + e], d1 = ei[E + e + 512];
        int p0 = atomicAdd(&cur[d0 >> BSH], 1);
        int p1 = atomicAdd(&cur[d1 >> BSH], 1);
        csr[p0] = (unsigned)s0 | ((unsigned)(d0 & (BSZ - 1)) << 17);
        csr[p1] = (unsigned)s1 | ((unsigned)(d1 & (BSZ - 1)) << 17);
    }
    for (; e < e1; e += 512) {
        int s0 = ei[e], d0 = ei[E + e];
        int p0 = atomicAdd(&cur[d0 >> BSH], 1);
        csr[p0] = (unsigned)s0 | ((unsigned)(d0 & (BSZ - 1)) << 17);
    }
}

// Per-bucket counting sort by dst node (in-place via LDS staging).
__global__ __launch_bounds__(256) void sortB_kernel(
    const int* __restrict__ bstart,
    unsigned* __restrict__ csr,
    int* __restrict__ nodeoff,       // [B*64+1]
    int B)
{
    __shared__ unsigned stage[SEG_CAP];
    __shared__ int cnt[BSZ];
    __shared__ int cur[BSZ];
    const int b = blockIdx.x, tid = threadIdx.x;
    const int e0 = bstart[b], e1 = bstart[b + 1];
    const int n = e1 - e0;

    if (tid < BSZ) cnt[tid] = 0;
    for (int i = tid; i < n; i += 256) stage[i] = csr[e0 + i];
    __syncthreads();
    for (int i = tid; i < n; i += 256) atomicAdd(&cnt[stage[i] >> 17], 1);
    __syncthreads();
    if (tid < BSZ) {
        int v = cnt[tid];
        int incl = v;
        #pragma unroll
        for (int o = 1; o < 64; o <<= 1) {
            int t = __shfl_up(incl, o);
            if ((tid & 63) >= o) incl += t;
        }
        int excl = e0 + incl - v;
        cur[tid] = excl;
        nodeoff[(size_t)b * BSZ + tid] = excl;
        if (b == B - 1 && tid == 0) nodeoff[(size_t)B * BSZ] = e1;
    }
    __syncthreads();
    for (int i = tid; i < n; i += 256) {
        unsigned pk = stage[i];
        int pos = atomicAdd(&cur[pk >> 17], 1);
        csr[pos] = pk & 0x1FFFFu;
    }
}

// Layer-1 aggregation, atomic-free: 4 lanes per node stride its contiguous
// edge list, accumulate 8 f32 in registers, shfl-combine, lane-0 epilogue.
__global__ __launch_bounds__(256) void agg1R_kernel(
    const int* __restrict__ nodeoff,
    const unsigned* __restrict__ csr,     // sorted src indices
    const unsigned short* __restrict__ yab, // [N,8] bf16
    const float* __restrict__ yr,    // [N,8] f32
    const float* __restrict__ b1,    // [8]
    const float* __restrict__ W2l,   // [10,8]
    const float* __restrict__ b2,    // [10]
    const float* __restrict__ W2r,   // [10,8]
    unsigned short* __restrict__ zlb, // [N,16] bf16 rows (32B)
    float* __restrict__ zrb,         // [N,12]  (col10 = invdeg)
    int N)
{
    __shared__ float wb[178];        // b1[8] | W2l[80] | b2[10] | W2r[80]
    const int tid = threadIdx.x;
    if (tid < 178)
        wb[tid] = (tid < 8) ? b1[tid] : (tid < 88) ? W2l[tid - 8]
                 : (tid < 98) ? b2[tid - 88] : W2r[tid - 98];
    __syncthreads();

    const int g = tid >> 2;          // node slot 0..63
    const int q = tid & 3;
    const int node = blockIdx.x * BSZ + g;
    const int gs = nodeoff[node], ge = nodeoff[node + 1];
    const uint4* ya4 = reinterpret_cast<const uint4*>(yab);

    float a[8];
    #pragma unroll
    for (int i = 0; i < 8; ++i) a[i] = 0.f;

    for (int e = gs + q; e < ge; e += 4) {
        unsigned s = csr[e];
        uint4 r = ya4[s];
        a[0] += bflo(r.x); a[1] += bfhi(r.x);
        a[2] += bflo(r.y); a[3] += bfhi(r.y);
        a[4] += bflo(r.z); a[5] += bfhi(r.z);
        a[6] += bflo(r.w); a[7] += bfhi(r.w);
    }
    #pragma unroll
    for (int i = 0; i < 8; ++i) {
        a[i] += __shfl_xor(a[i], 1);
        a[i] += __shfl_xor(a[i], 2);
    }

    if (q != 0 || node >= N) return;
    const int deg = ge - gs;
    const float inv = 1.f / fmaxf((float)deg, 1.f);
    const f4v* yr4 = reinterpret_cast<const f4v*>(yr + (size_t)node * 8);
    f4v r0 = yr4[0], r1 = yr4[1];
    const float rr[8] = {r0.x, r0.y, r0.z, r0.w, r1.x, r1.y, r1.z, r1.w};

    float h[8];
    #pragma unroll
    for (int t = 0; t < 8; ++t) {
        float v = a[t] * inv + wb[t] + rr[t];
        h[t] = v > 0.f ? v : expm1f(v);   // ELU(alpha=1)
    }

    float zlv[10], zrv[10];
    #pragma unroll
    for (int k = 0; k < 10; ++k) {
        float al = 0.f, ar = wb[88 + k];
        #pragma unroll
        for (int t = 0; t < 8; ++t) {
            al += wb[8 + k * 8 + t]  * h[t];
            ar += wb[98 + k * 8 + t] * h[t];
        }
        zlv[k] = al; zrv[k] = ar;
    }

    uint4 h0, h1;
    h0.x = f2bf(zlv[0]) | (f2bf(zlv[1]) << 16);
    h0.y = f2bf(zlv[2]) | (f2bf(zlv[3]) << 16);
    h0.z = f2bf(zlv[4]);
    h0.w = 0u;
    h1.x = f2bf(zlv[5]) | (f2bf(zlv[6]) << 16);
    h1.y = f2bf(zlv[7]) | (f2bf(zlv[8]) << 16);
    h1.z = f2bf(zlv[9]);
    h1.w = 0u;
    uint4* zl4w = reinterpret_cast<uint4*>(zlb + (size_t)node * 16);
    zl4w[0] = h0;
    zl4w[1] = h1;

    float4* zr4w = reinterpret_cast<float4*>(zrb + (size_t)node * 12);
    zr4w[0] = make_float4(zrv[0], zrv[1], zrv[2], zrv[3]);
    zr4w[1] = make_float4(zrv[4], zrv[5], zrv[6], zrv[7]);
    zr4w[2] = make_float4(zrv[8], zrv[9], inv, 0.f);   // col10 = invdeg
}

// Layer-2 aggregation, atomic-free: 4 lanes per node, register accumulate
// 10 f32, shfl-combine, lane-0 does mean + r-branch + log-softmax.
__global__ __launch_bounds__(256) void agg2R_kernel(
    const int* __restrict__ nodeoff,
    const unsigned* __restrict__ csr,     // sorted src indices
    const unsigned short* __restrict__ zlb, // [N,16] bf16
    const float* __restrict__ zrb,   // [N,12] (col10 = invdeg)
    float* __restrict__ out,         // [N,10]
    int N)
{
    const int tid = threadIdx.x;
    const int g = tid >> 2;
    const int q = tid & 3;
    const int node = blockIdx.x * BSZ + g;
    const int gs = nodeoff[node], ge = nodeoff[node + 1];
    const uint4* zl4 = reinterpret_cast<const uint4*>(zlb);

    float a[10];
    #pragma unroll
    for (int i = 0; i < 10; ++i) a[i] = 0.f;

    for (int e = gs + q; e < ge; e += 4) {
        unsigned s = csr[e];
        uint4 rA = zl4[(size_t)s * 2];
        uint4 rB = zl4[(size_t)s * 2 + 1];
        a[0] += bflo(rA.x); a[1] += bfhi(rA.x);
        a[2] += bflo(rA.y); a[3] += bfhi(rA.y);
        a[4] += bflo(rA.z);
        a[5] += bflo(rB.x); a[6] += bfhi(rB.x);
        a[7] += bflo(rB.y); a[8] += bfhi(rB.y);
        a[9] += bflo(rB.z);
    }
    #pragma unroll
    for (int i = 0; i < 10; ++i) {
        a[i] += __shfl_xor(a[i], 1);
        a[i] += __shfl_xor(a[i], 2);
    }

    if (q != 0 || node >= N) return;
    const float* zr = zrb + (size_t)node * 12;
    const float inv = zr[10];
    float v[10];
    float mx = -1e30f;
    #pragma unroll
    for (int k = 0; k < 10; ++k) {
        v[k] = a[k] * inv + zr[k];
        mx = fmaxf(mx, v[k]);
    }
    float ssum = 0.f;
    #pragma unroll
    for (int k = 0; k < 10; ++k) ssum += expf(v[k] - mx);
    const float lse = mx + logf(ssum);
    float2* o = reinterpret_cast<float2*>(out + (size_t)node * 10);
    o[0] = make_float2(v[0] - lse, v[1] - lse);
    o[1] = make_float2(v[2] - lse, v[3] - lse);
    o[2] = make_float2(v[4] - lse, v[5] - lse);
    o[3] = make_float2(v[6] - lse, v[7] - lse);
    o[4] = make_float2(v[8] - lse, v[9] - lse);
}

extern "C" void kernel_launch(void* const* d_in, const int* in_sizes, int n_in,
                              void* d_out, int out_size, void* d_ws, size_t ws_size,
                              hipStream_t stream) {
    const float* x   = (const float*)d_in[0];
    const int*   ei  = (const int*)d_in[1];
    const float* W1l = (const float*)d_in[2];
    const float* b1l = (const float*)d_in[3];
    const float* W1r = (const float*)d_in[4];
    const float* W2l = (const float*)d_in[5];
    const float* b2l = (const float*)d_in[6];
    const float* W2r = (const float*)d_in[7];
    float* out = (float*)d_out;

    const int N = in_sizes[0] / 500;
    const int E = in_sizes[1] / 2;
    const int B = (N + BSZ - 1) >> BSH;       // buckets of BSZ nodes
    const int chunk = (E + P_BLOCKS - 1) / P_BLOCKS;

    // workspace: ints first, then 16B-aligned arrays (~33 MB)
    int* hist_g  = (int*)d_ws;                       // [B*P_BLOCKS] (hist, then base in-place)
    int* tot     = hist_g + (size_t)B * P_BLOCKS;    // [B]
    int* bstart  = tot + B;                          // [B+1]
    int* nodeoff = bstart + (B + 1);                 // [B*64+1]
    unsigned* csr = (unsigned*)(nodeoff + (size_t)B * BSZ + 1); // [E]
    size_t off = ((char*)(csr + E) - (char*)d_ws + 15) & ~(size_t)15;
    unsigned short* yab = (unsigned short*)((char*)d_ws + off);  // [N,8] bf16
    off = (off + (size_t)N * 16 + 15) & ~(size_t)15;
    unsigned short* zlb = (unsigned short*)((char*)d_ws + off);  // [N,16] bf16
    off = (off + (size_t)N * 32 + 15) & ~(size_t)15;
    float* yr  = (float*)((char*)d_ws + off);                    // [N,8] f32
    float* zrb = yr + (size_t)8 * N;                             // [N,12] f32

    proj1_kernel<<<1024, 256, 0, stream>>>(x, W1l, W1r, yab, yr, N);
    hist_kernel<<<P_BLOCKS, 512, 0, stream>>>(ei, E, chunk, B, hist_g);
    bsum_kernel<<<B, 256, 0, stream>>>(hist_g, tot);
    base_kernel<<<B, 256, 0, stream>>>(hist_g, tot, B, bstart);
    scatter2_kernel<<<P_BLOCKS, 512, 0, stream>>>(ei, E, chunk, B, hist_g, csr);
    sortB_kernel<<<B, 256, 0, stream>>>(bstart, csr, nodeoff, B);
    agg1R_kernel<<<B, 256, 0, stream>>>(nodeoff, csr, yab, yr, b1l, W2l, b2l, W2r,
                                        zlb, zrb, N);
    agg2R_kernel<<<B, 256, 0, stream>>>(nodeoff, csr, zlb, zrb, out, N);
}